// Round 1
// baseline (17055.864 us; speedup 1.0000x reference)
//
#include <hip/hip_runtime.h>
#include <math.h>

#define SELU_SCALE 1.0507009873554805f
#define SELU_ALPHA 1.6732632423543772f

// ---- monotone float <-> uint key for atomic max on floats ----
__device__ __forceinline__ unsigned int fkey(float x) {
    unsigned int b = __float_as_uint(x);
    return (b & 0x80000000u) ? ~b : (b | 0x80000000u);
}
__device__ __forceinline__ float funkey(unsigned int k) {
    unsigned int b = (k & 0x80000000u) ? (k ^ 0x80000000u) : ~k;
    return __uint_as_float(b);
}

// ---- degree / normalization ----
__global__ void deg_init_kernel(float* __restrict__ deg, int N) {
    int i = blockIdx.x * blockDim.x + threadIdx.x;
    if (i < N) deg[i] = 1.0f;  // self loop
}
__global__ void deg_count_kernel(const int* __restrict__ dst, float* __restrict__ deg, int E) {
    int e = blockIdx.x * blockDim.x + threadIdx.x;
    if (e < E) atomicAdd(&deg[dst[e]], 1.0f);
}
__global__ void deg_rsqrt_kernel(float* __restrict__ deg, int N) {
    int i = blockIdx.x * blockDim.x + threadIdx.x;
    if (i < N) deg[i] = rsqrtf(deg[i]);
}

// ---- per-layer: u = (h @ W) * dinv[n]; m = key(u)  (self-loop init) ----
template <int FIN, int FOUT>
__global__ void gemm_scale_kernel(const float* __restrict__ h,
                                  const float* __restrict__ W,
                                  const float* __restrict__ dinv,
                                  float* __restrict__ u,
                                  unsigned int* __restrict__ m,
                                  int N) {
    __shared__ float Ws[FIN * FOUT];
    for (int i = threadIdx.x; i < FIN * FOUT; i += blockDim.x) Ws[i] = W[i];
    __syncthreads();
    int idx = blockIdx.x * blockDim.x + threadIdx.x;  // N*FOUT <= 36e6 < 2^31
    if (idx >= N * FOUT) return;
    int n = idx / FOUT;
    int fo = idx - n * FOUT;
    const float* hr = h + (long long)n * FIN;
    float acc = 0.0f;
#pragma unroll
    for (int fi = 0; fi < FIN; ++fi) acc += hr[fi] * Ws[fi * FOUT + fo];
    float v = acc * dinv[n];
    u[idx] = v;
    m[idx] = fkey(v);
}

// ---- per-layer: scatter-max u[src] into m[dst] ----
template <int FOUT>
__global__ void scatter_max_kernel(const int* __restrict__ src,
                                   const int* __restrict__ dst,
                                   const float* __restrict__ u,
                                   unsigned int* __restrict__ m,
                                   int E) {
    int e = blockIdx.x * blockDim.x + threadIdx.x;
    if (e >= E) return;
    int s = src[e];
    int d = dst[e];
    const float* ur = u + (long long)s * FOUT;
    unsigned int* mr = m + (long long)d * FOUT;
#pragma unroll
    for (int f = 0; f < FOUT; ++f) atomicMax(&mr[f], fkey(ur[f]));
}

// ---- per-layer: h_out = selu(dinv[n] * decode(m) + b[f]) ----
template <int FOUT>
__global__ void finish_kernel(const unsigned int* __restrict__ m,
                              const float* __restrict__ dinv,
                              const float* __restrict__ b,
                              float* __restrict__ hout,
                              int N) {
    int idx = blockIdx.x * blockDim.x + threadIdx.x;
    if (idx >= N * FOUT) return;
    int n = idx / FOUT;
    int f = idx - n * FOUT;
    float v = dinv[n] * funkey(m[idx]) + b[f];
    hout[idx] = (v > 0.0f) ? (SELU_SCALE * v) : (SELU_SCALE * SELU_ALPHA * (expf(v) - 1.0f));
}

// ---- pooling ----
__global__ void zero_kernel(float* __restrict__ p, int n) {
    int i = blockIdx.x * blockDim.x + threadIdx.x;
    if (i < n) p[i] = 0.0f;
}
__global__ void pool_kernel(const float* __restrict__ h,
                            const int* __restrict__ batch,
                            float* __restrict__ pooled,
                            int N) {
    int idx = blockIdx.x * blockDim.x + threadIdx.x;  // N*36
    if (idx >= N * 36) return;
    int n = idx / 36;
    int f = idx - n * 36;
    atomicAdd(&pooled[(long long)batch[n] * 36 + f], h[idx]);
}

// ---- MLP head ----
__global__ void mlp1_kernel(const float* __restrict__ pooled,
                            const float* __restrict__ lw1,
                            const float* __restrict__ lb1,
                            float* __restrict__ y1,
                            int G) {
    __shared__ float Ws[36 * 96];
    for (int i = threadIdx.x; i < 36 * 96; i += blockDim.x) Ws[i] = lw1[i];
    __syncthreads();
    int idx = blockIdx.x * blockDim.x + threadIdx.x;  // G*96
    if (idx >= G * 96) return;
    int g = idx / 96;
    int j = idx - g * 96;
    const float* pr = pooled + (long long)g * 36;
    float acc = lb1[j];
#pragma unroll
    for (int k = 0; k < 36; ++k) acc += pr[k] * Ws[k * 96 + j];
    y1[idx] = fmaxf(acc, 0.0f);
}
__global__ void mlp2_kernel(const float* __restrict__ y1,
                            const float* __restrict__ lw2,
                            const float* __restrict__ lb2,
                            float* __restrict__ out,
                            int G) {
    __shared__ float Ws[96 * 27];
    for (int i = threadIdx.x; i < 96 * 27; i += blockDim.x) Ws[i] = lw2[i];
    __syncthreads();
    int idx = blockIdx.x * blockDim.x + threadIdx.x;  // G*27
    if (idx >= G * 27) return;
    int g = idx / 27;
    int c = idx - g * 27;
    const float* yr = y1 + (long long)g * 96;
    float acc = lb2[c];
#pragma unroll
    for (int k = 0; k < 96; ++k) acc += yr[k] * Ws[k * 27 + c];
    out[idx] = fmaxf(acc, 0.0f);
}

static inline int cdiv(long long a, int b) { return (int)((a + b - 1) / b); }

extern "C" void kernel_launch(void* const* d_in, const int* in_sizes, int n_in,
                              void* d_out, int out_size, void* d_ws, size_t ws_size,
                              hipStream_t stream) {
    const float* x     = (const float*)d_in[0];
    const int*   ei    = (const int*)d_in[1];
    const int*   batch = (const int*)d_in[2];
    // d_in[3] = num_graphs (scalar), unused on host
    const float* W1  = (const float*)d_in[4];
    const float* b1  = (const float*)d_in[5];
    const float* W2  = (const float*)d_in[6];
    const float* b2  = (const float*)d_in[7];
    const float* W3  = (const float*)d_in[8];
    const float* b3  = (const float*)d_in[9];
    const float* W4  = (const float*)d_in[10];
    const float* b4  = (const float*)d_in[11];
    const float* lw1 = (const float*)d_in[12];
    const float* lb1 = (const float*)d_in[13];
    const float* lw2 = (const float*)d_in[14];
    const float* lb2 = (const float*)d_in[15];
    float* out = (float*)d_out;

    const int N = in_sizes[0] / 75;
    const int E = in_sizes[1] / 2;
    const int G = out_size / 27;
    const int* srcp = ei;
    const int* dstp = ei + E;

    // workspace carve-up
    char* ws = (char*)d_ws;
    size_t off = 0;
    auto carve = [&](size_t bytes) -> char* {
        char* p = ws + off;
        off = (off + bytes + 255) & ~(size_t)255;
        return p;
    };
    float*        dinv   = (float*)carve((size_t)N * 4);
    float*        A      = (float*)carve((size_t)N * 36 * 4);  // activations
    float*        B      = (float*)carve((size_t)N * 36 * 4);  // u = (h@W)*dinv
    unsigned int* C      = (unsigned int*)carve((size_t)N * 36 * 4);  // max keys
    float*        pooled = (float*)carve((size_t)G * 36 * 4);
    float*        y1     = (float*)carve((size_t)G * 96 * 4);
    (void)ws_size; (void)n_in;

    const int BLK = 256;

    // normalization (same for all 4 layers)
    deg_init_kernel<<<cdiv(N, BLK), BLK, 0, stream>>>(dinv, N);
    deg_count_kernel<<<cdiv(E, BLK), BLK, 0, stream>>>(dstp, dinv, E);
    deg_rsqrt_kernel<<<cdiv(N, BLK), BLK, 0, stream>>>(dinv, N);

    // layer 1: 75 -> 15
    gemm_scale_kernel<75, 15><<<cdiv((long long)N * 15, BLK), BLK, 0, stream>>>(x, W1, dinv, B, C, N);
    scatter_max_kernel<15><<<cdiv(E, BLK), BLK, 0, stream>>>(srcp, dstp, B, C, E);
    finish_kernel<15><<<cdiv((long long)N * 15, BLK), BLK, 0, stream>>>(C, dinv, b1, A, N);

    // layer 2: 15 -> 20
    gemm_scale_kernel<15, 20><<<cdiv((long long)N * 20, BLK), BLK, 0, stream>>>(A, W2, dinv, B, C, N);
    scatter_max_kernel<20><<<cdiv(E, BLK), BLK, 0, stream>>>(srcp, dstp, B, C, E);
    finish_kernel<20><<<cdiv((long long)N * 20, BLK), BLK, 0, stream>>>(C, dinv, b2, A, N);

    // layer 3: 20 -> 27
    gemm_scale_kernel<20, 27><<<cdiv((long long)N * 27, BLK), BLK, 0, stream>>>(A, W3, dinv, B, C, N);
    scatter_max_kernel<27><<<cdiv(E, BLK), BLK, 0, stream>>>(srcp, dstp, B, C, E);
    finish_kernel<27><<<cdiv((long long)N * 27, BLK), BLK, 0, stream>>>(C, dinv, b3, A, N);

    // layer 4: 27 -> 36
    gemm_scale_kernel<27, 36><<<cdiv((long long)N * 36, BLK), BLK, 0, stream>>>(A, W4, dinv, B, C, N);
    scatter_max_kernel<36><<<cdiv(E, BLK), BLK, 0, stream>>>(srcp, dstp, B, C, E);
    finish_kernel<36><<<cdiv((long long)N * 36, BLK), BLK, 0, stream>>>(C, dinv, b4, A, N);

    // pool: segment_sum over sorted batch ids
    zero_kernel<<<cdiv((long long)G * 36, BLK), BLK, 0, stream>>>(pooled, G * 36);
    pool_kernel<<<cdiv((long long)N * 36, BLK), BLK, 0, stream>>>(A, batch, pooled, N);

    // MLP head
    mlp1_kernel<<<cdiv((long long)G * 96, BLK), BLK, 0, stream>>>(pooled, lw1, lb1, y1, G);
    mlp2_kernel<<<cdiv((long long)G * 27, BLK), BLK, 0, stream>>>(y1, lw2, lb2, out, G);
}

// Round 2
// 2095.326 us; speedup vs baseline: 8.1400x; 8.1400x over previous
//
#include <hip/hip_runtime.h>
#include <math.h>

#define SELU_SCALE 1.0507009873554805f
#define SELU_ALPHA 1.6732632423543772f

static inline int cdiv(long long a, int b) { return (int)((a + b - 1) / b); }

// ===================== edge preprocessing (once, reused by all layers) =====================

__global__ void zero_int_kernel(int* __restrict__ p, int n) {
    int i = blockIdx.x * blockDim.x + threadIdx.x;
    if (i < n) p[i] = 0;
}

__global__ void hist_kernel(const int* __restrict__ dst, int* __restrict__ cnt, int E) {
    int e = blockIdx.x * blockDim.x + threadIdx.x;
    if (e < E) atomicAdd(&cnt[dst[e]], 1);
}

__global__ void dinv_kernel(const int* __restrict__ cnt, float* __restrict__ dinv, int N) {
    int i = blockIdx.x * blockDim.x + threadIdx.x;
    if (i < N) dinv[i] = rsqrtf((float)cnt[i] + 1.0f);  // +1 self loop
}

// ---- 3-phase exclusive scan of cnt[0..N) -> row_ptr, chunk = 1024 per block ----
__global__ void scan_partial_kernel(const int* __restrict__ cnt, int* __restrict__ bsum, int N) {
    __shared__ int sh[256];
    int base = blockIdx.x * 1024;
    int t = threadIdx.x;
    int s = 0;
#pragma unroll
    for (int k = 0; k < 4; ++k) {
        int i = base + t * 4 + k;
        if (i < N) s += cnt[i];
    }
    sh[t] = s;
    __syncthreads();
    for (int o = 128; o > 0; o >>= 1) {
        if (t < o) sh[t] += sh[t + o];
        __syncthreads();
    }
    if (t == 0) bsum[blockIdx.x] = sh[0];
}

__global__ void scan_bsum_kernel(int* __restrict__ bsum, int nb) {
    if (blockIdx.x == 0 && threadIdx.x == 0) {
        int acc = 0;
        for (int i = 0; i < nb; ++i) { int v = bsum[i]; bsum[i] = acc; acc += v; }
    }
}

__global__ void scan_final_kernel(const int* __restrict__ cnt, const int* __restrict__ bsum,
                                  int* __restrict__ row_ptr, int N, int E) {
    __shared__ int sh[256];
    int base = blockIdx.x * 1024;
    int t = threadIdx.x;
    int i0 = base + t * 4;
    int v0 = (i0 + 0 < N) ? cnt[i0 + 0] : 0;
    int v1 = (i0 + 1 < N) ? cnt[i0 + 1] : 0;
    int v2 = (i0 + 2 < N) ? cnt[i0 + 2] : 0;
    int v3 = (i0 + 3 < N) ? cnt[i0 + 3] : 0;
    sh[t] = v0 + v1 + v2 + v3;
    __syncthreads();
    for (int o = 1; o < 256; o <<= 1) {
        int y = (t >= o) ? sh[t - o] : 0;
        __syncthreads();
        sh[t] += y;
        __syncthreads();
    }
    int off = bsum[blockIdx.x] + ((t > 0) ? sh[t - 1] : 0);
    if (i0 + 0 < N) row_ptr[i0 + 0] = off;  off += v0;
    if (i0 + 1 < N) row_ptr[i0 + 1] = off;  off += v1;
    if (i0 + 2 < N) row_ptr[i0 + 2] = off;  off += v2;
    if (i0 + 3 < N) row_ptr[i0 + 3] = off;
    if (blockIdx.x == 0 && t == 0) row_ptr[N] = E;
}

__global__ void fill_sorted_kernel(const int* __restrict__ src, const int* __restrict__ dst,
                                   const int* __restrict__ row_ptr, int* __restrict__ cursor,
                                   int* __restrict__ sorted_src, int E) {
    int e = blockIdx.x * blockDim.x + threadIdx.x;
    if (e >= E) return;
    int d = dst[e];
    int pos = row_ptr[d] + atomicAdd(&cursor[d], 1);
    sorted_src[pos] = src[e];
}

// ===================== per-layer kernels =====================

// u = (h @ W) * dinv[n]
template <int FIN, int FOUT>
__global__ void gemm_scale_kernel(const float* __restrict__ h,
                                  const float* __restrict__ W,
                                  const float* __restrict__ dinv,
                                  float* __restrict__ u,
                                  int N) {
    __shared__ float Ws[FIN * FOUT];
    for (int i = threadIdx.x; i < FIN * FOUT; i += blockDim.x) Ws[i] = W[i];
    __syncthreads();
    int idx = blockIdx.x * blockDim.x + threadIdx.x;
    if (idx >= N * FOUT) return;
    int n = idx / FOUT;
    int fo = idx - n * FOUT;
    const float* hr = h + (long long)n * FIN;
    float acc = 0.0f;
#pragma unroll
    for (int fi = 0; fi < FIN; ++fi) acc += hr[fi] * Ws[fi * FOUT + fo];
    u[idx] = acc * dinv[n];
}

// hout[n,f] = selu(dinv[n] * max(u[n,f], max_{j in row} u[src_j, f]) + b[f])
template <int FOUT>
__global__ void gather_max_selu_kernel(const float* __restrict__ u,
                                       const int* __restrict__ row_ptr,
                                       const int* __restrict__ sorted_src,
                                       const float* __restrict__ dinv,
                                       const float* __restrict__ b,
                                       float* __restrict__ hout,
                                       int N) {
    int idx = blockIdx.x * blockDim.x + threadIdx.x;
    if (idx >= N * FOUT) return;
    int n = idx / FOUT;
    int f = idx - n * FOUT;
    float acc = u[(long long)n * FOUT + f];  // self loop
    int j0 = row_ptr[n], j1 = row_ptr[n + 1];
    for (int j = j0; j < j1; ++j) {
        int s = sorted_src[j];
        acc = fmaxf(acc, u[(long long)s * FOUT + f]);
    }
    float v = dinv[n] * acc + b[f];
    hout[idx] = (v > 0.0f) ? (SELU_SCALE * v) : (SELU_SCALE * SELU_ALPHA * (expf(v) - 1.0f));
}

// ===================== pooling (segmented sum over sorted batch ids) =====================

__global__ void pool_kernel(const float* __restrict__ h,
                            const int* __restrict__ batch,
                            float* __restrict__ pooled,
                            int N, int G) {
    int g = blockIdx.x;
    int t = threadIdx.x;
    __shared__ int s_lo, s_hi;
    if (t == 0) {
        int lo = 0, hi = N;
        while (lo < hi) { int mid = (lo + hi) >> 1; if (batch[mid] < g) lo = mid + 1; else hi = mid; }
        s_lo = lo;
        int lo2 = lo, hi2 = N;
        while (lo2 < hi2) { int mid = (lo2 + hi2) >> 1; if (batch[mid] < g + 1) lo2 = mid + 1; else hi2 = mid; }
        s_hi = lo2;
    }
    __syncthreads();
    if (t >= 36) return;
    float acc = 0.0f;
    for (int n = s_lo; n < s_hi; ++n) acc += h[(long long)n * 36 + t];
    pooled[(long long)g * 36 + t] = acc;
}

// ===================== MLP head =====================

__global__ void mlp1_kernel(const float* __restrict__ pooled,
                            const float* __restrict__ lw1,
                            const float* __restrict__ lb1,
                            float* __restrict__ y1,
                            int G) {
    __shared__ float Ws[36 * 96];
    for (int i = threadIdx.x; i < 36 * 96; i += blockDim.x) Ws[i] = lw1[i];
    __syncthreads();
    int idx = blockIdx.x * blockDim.x + threadIdx.x;
    if (idx >= G * 96) return;
    int g = idx / 96;
    int j = idx - g * 96;
    const float* pr = pooled + (long long)g * 36;
    float acc = lb1[j];
#pragma unroll
    for (int k = 0; k < 36; ++k) acc += pr[k] * Ws[k * 96 + j];
    y1[idx] = fmaxf(acc, 0.0f);
}

__global__ void mlp2_kernel(const float* __restrict__ y1,
                            const float* __restrict__ lw2,
                            const float* __restrict__ lb2,
                            float* __restrict__ out,
                            int G) {
    __shared__ float Ws[96 * 27];
    for (int i = threadIdx.x; i < 96 * 27; i += blockDim.x) Ws[i] = lw2[i];
    __syncthreads();
    int idx = blockIdx.x * blockDim.x + threadIdx.x;
    if (idx >= G * 27) return;
    int g = idx / 27;
    int c = idx - g * 27;
    const float* yr = y1 + (long long)g * 96;
    float acc = lb2[c];
#pragma unroll
    for (int k = 0; k < 96; ++k) acc += yr[k] * Ws[k * 27 + c];
    out[idx] = fmaxf(acc, 0.0f);
}

// ===================== launch =====================

extern "C" void kernel_launch(void* const* d_in, const int* in_sizes, int n_in,
                              void* d_out, int out_size, void* d_ws, size_t ws_size,
                              hipStream_t stream) {
    const float* x     = (const float*)d_in[0];
    const int*   ei    = (const int*)d_in[1];
    const int*   batch = (const int*)d_in[2];
    const float* W1  = (const float*)d_in[4];
    const float* b1  = (const float*)d_in[5];
    const float* W2  = (const float*)d_in[6];
    const float* b2  = (const float*)d_in[7];
    const float* W3  = (const float*)d_in[8];
    const float* b3  = (const float*)d_in[9];
    const float* W4  = (const float*)d_in[10];
    const float* b4  = (const float*)d_in[11];
    const float* lw1 = (const float*)d_in[12];
    const float* lb1 = (const float*)d_in[13];
    const float* lw2 = (const float*)d_in[14];
    const float* lb2 = (const float*)d_in[15];
    float* out = (float*)d_out;

    const int N = in_sizes[0] / 75;
    const int E = in_sizes[1] / 2;
    const int G = out_size / 27;
    const int* srcp = ei;
    const int* dstp = ei + E;

    // workspace carve-up
    char* ws = (char*)d_ws;
    size_t off = 0;
    auto carve = [&](size_t bytes) -> char* {
        char* p = ws + off;
        off = (off + bytes + 255) & ~(size_t)255;
        return p;
    };
    int*   cnt        = (int*)carve((size_t)N * 4);          // histogram, later cursor
    int*   row_ptr    = (int*)carve((size_t)(N + 1) * 4);
    int*   sorted_src = (int*)carve((size_t)E * 4);
    int*   bsum       = (int*)carve((size_t)cdiv(N, 1024) * 4 + 4);
    float* dinv       = (float*)carve((size_t)N * 4);
    float* A          = (float*)carve((size_t)N * 36 * 4);   // activations
    float* B          = (float*)carve((size_t)N * 36 * 4);   // u = (h@W)*dinv
    float* pooled     = (float*)carve((size_t)G * 36 * 4);
    float* y1         = (float*)carve((size_t)G * 96 * 4);
    (void)ws_size; (void)n_in;

    const int BLK = 256;
    const int nb = cdiv(N, 1024);

    // ---- edge preprocessing: histogram -> dinv -> scan -> CSR fill ----
    zero_int_kernel<<<cdiv(N, BLK), BLK, 0, stream>>>(cnt, N);
    hist_kernel<<<cdiv(E, BLK), BLK, 0, stream>>>(dstp, cnt, E);
    dinv_kernel<<<cdiv(N, BLK), BLK, 0, stream>>>(cnt, dinv, N);
    scan_partial_kernel<<<nb, 256, 0, stream>>>(cnt, bsum, N);
    scan_bsum_kernel<<<1, 64, 0, stream>>>(bsum, nb);
    scan_final_kernel<<<nb, 256, 0, stream>>>(cnt, bsum, row_ptr, N, E);
    zero_int_kernel<<<cdiv(N, BLK), BLK, 0, stream>>>(cnt, N);  // cursor
    fill_sorted_kernel<<<cdiv(E, BLK), BLK, 0, stream>>>(srcp, dstp, row_ptr, cnt, sorted_src, E);

    // ---- layer 1: 75 -> 15 ----
    gemm_scale_kernel<75, 15><<<cdiv((long long)N * 15, BLK), BLK, 0, stream>>>(x, W1, dinv, B, N);
    gather_max_selu_kernel<15><<<cdiv((long long)N * 15, BLK), BLK, 0, stream>>>(B, row_ptr, sorted_src, dinv, b1, A, N);

    // ---- layer 2: 15 -> 20 ----
    gemm_scale_kernel<15, 20><<<cdiv((long long)N * 20, BLK), BLK, 0, stream>>>(A, W2, dinv, B, N);
    gather_max_selu_kernel<20><<<cdiv((long long)N * 20, BLK), BLK, 0, stream>>>(B, row_ptr, sorted_src, dinv, b2, A, N);

    // ---- layer 3: 20 -> 27 ----
    gemm_scale_kernel<20, 27><<<cdiv((long long)N * 27, BLK), BLK, 0, stream>>>(A, W3, dinv, B, N);
    gather_max_selu_kernel<27><<<cdiv((long long)N * 27, BLK), BLK, 0, stream>>>(B, row_ptr, sorted_src, dinv, b3, A, N);

    // ---- layer 4: 27 -> 36 ----
    gemm_scale_kernel<27, 36><<<cdiv((long long)N * 36, BLK), BLK, 0, stream>>>(A, W4, dinv, B, N);
    gather_max_selu_kernel<36><<<cdiv((long long)N * 36, BLK), BLK, 0, stream>>>(B, row_ptr, sorted_src, dinv, b4, A, N);

    // ---- pool: segmented sum (batch_vec is sorted) ----
    pool_kernel<<<G, 64, 0, stream>>>(A, batch, pooled, N, G);

    // ---- MLP head ----
    mlp1_kernel<<<cdiv((long long)G * 96, BLK), BLK, 0, stream>>>(pooled, lw1, lb1, y1, G);
    mlp2_kernel<<<cdiv((long long)G * 27, BLK), BLK, 0, stream>>>(y1, lw2, lb2, out, G);
}

// Round 3
// 1465.584 us; speedup vs baseline: 11.6376x; 1.4297x over previous
//
#include <hip/hip_runtime.h>
#include <math.h>

#define SELU_SCALE 1.0507009873554805f
#define SELU_ALPHA 1.6732632423543772f

static inline int cdiv(long long a, int b) { return (int)((a + b - 1) / b); }

// ===================== edge preprocessing (once, reused by all layers) =====================

__global__ void zero_int_kernel(int* __restrict__ p, int n) {
    int i = blockIdx.x * blockDim.x + threadIdx.x;
    if (i < n) p[i] = 0;
}

__global__ void hist_kernel(const int* __restrict__ dst, int* __restrict__ cnt, int E) {
    int e = blockIdx.x * blockDim.x + threadIdx.x;
    if (e < E) atomicAdd(&cnt[dst[e]], 1);
}

__global__ void dinv_kernel(const int* __restrict__ cnt, float* __restrict__ dinv, int N) {
    int i = blockIdx.x * blockDim.x + threadIdx.x;
    if (i < N) dinv[i] = rsqrtf((float)cnt[i] + 1.0f);  // +1 self loop
}

// ---- 3-phase exclusive scan of cnt[0..N) -> row_ptr, chunk = 1024 per block ----
__global__ void scan_partial_kernel(const int* __restrict__ cnt, int* __restrict__ bsum, int N) {
    __shared__ int sh[256];
    int base = blockIdx.x * 1024;
    int t = threadIdx.x;
    int s = 0;
#pragma unroll
    for (int k = 0; k < 4; ++k) {
        int i = base + t * 4 + k;
        if (i < N) s += cnt[i];
    }
    sh[t] = s;
    __syncthreads();
    for (int o = 128; o > 0; o >>= 1) {
        if (t < o) sh[t] += sh[t + o];
        __syncthreads();
    }
    if (t == 0) bsum[blockIdx.x] = sh[0];
}

__global__ void scan_bsum_kernel(int* __restrict__ bsum, int nb) {
    if (blockIdx.x == 0 && threadIdx.x == 0) {
        int acc = 0;
        for (int i = 0; i < nb; ++i) { int v = bsum[i]; bsum[i] = acc; acc += v; }
    }
}

__global__ void scan_final_kernel(const int* __restrict__ cnt, const int* __restrict__ bsum,
                                  int* __restrict__ row_ptr, int N, int E) {
    __shared__ int sh[256];
    int base = blockIdx.x * 1024;
    int t = threadIdx.x;
    int i0 = base + t * 4;
    int v0 = (i0 + 0 < N) ? cnt[i0 + 0] : 0;
    int v1 = (i0 + 1 < N) ? cnt[i0 + 1] : 0;
    int v2 = (i0 + 2 < N) ? cnt[i0 + 2] : 0;
    int v3 = (i0 + 3 < N) ? cnt[i0 + 3] : 0;
    sh[t] = v0 + v1 + v2 + v3;
    __syncthreads();
    for (int o = 1; o < 256; o <<= 1) {
        int y = (t >= o) ? sh[t - o] : 0;
        __syncthreads();
        sh[t] += y;
        __syncthreads();
    }
    int off = bsum[blockIdx.x] + ((t > 0) ? sh[t - 1] : 0);
    if (i0 + 0 < N) row_ptr[i0 + 0] = off;  off += v0;
    if (i0 + 1 < N) row_ptr[i0 + 1] = off;  off += v1;
    if (i0 + 2 < N) row_ptr[i0 + 2] = off;  off += v2;
    if (i0 + 3 < N) row_ptr[i0 + 3] = off;
    if (blockIdx.x == 0 && t == 0) row_ptr[N] = E;
}

__global__ void fill_sorted_kernel(const int* __restrict__ src, const int* __restrict__ dst,
                                   const int* __restrict__ row_ptr, int* __restrict__ cursor,
                                   int* __restrict__ sorted_src, int E) {
    int e = blockIdx.x * blockDim.x + threadIdx.x;
    if (e >= E) return;
    int d = dst[e];
    int pos = row_ptr[d] + atomicAdd(&cursor[d], 1);
    sorted_src[pos] = src[e];
}

// ===================== per-layer kernels =====================

// thread per node: u[n, 0..SOUT) = (h[n,:] @ W) * dinv[n], pad cols = 0.
// W indices are wave-uniform compile-time -> scalar loads (no LDS).
template <int FIN, int SIN, int FOUT, int SOUT, bool VEC_IN>
__global__ void gemm_scale_kernel(const float* __restrict__ h,
                                  const float* __restrict__ W,
                                  const float* __restrict__ dinv,
                                  float* __restrict__ u,
                                  int N) {
    int n = blockIdx.x * blockDim.x + threadIdx.x;
    if (n >= N) return;
    const float* hr = h + (long long)n * SIN;
    float acc[FOUT];
#pragma unroll
    for (int c = 0; c < FOUT; ++c) acc[c] = 0.0f;

    if (VEC_IN) {
#pragma unroll
        for (int fi4 = 0; fi4 < SIN / 4; ++fi4) {
            float4 hv = *reinterpret_cast<const float4*>(hr + fi4 * 4);
            const float hvv[4] = {hv.x, hv.y, hv.z, hv.w};
#pragma unroll
            for (int k = 0; k < 4; ++k) {
                const int fi = fi4 * 4 + k;
                if (fi < FIN) {
#pragma unroll
                    for (int c = 0; c < FOUT; ++c) acc[c] += hvv[k] * W[fi * FOUT + c];
                }
            }
        }
    } else {
#pragma unroll
        for (int fi = 0; fi < FIN; ++fi) {
            float hv = hr[fi];
#pragma unroll
            for (int c = 0; c < FOUT; ++c) acc[c] += hv * W[fi * FOUT + c];
        }
    }
    float dv = dinv[n];
    float* ur = u + (long long)n * SOUT;
#pragma unroll
    for (int g = 0; g < SOUT / 4; ++g) {
        float4 w;
        w.x = (4 * g + 0 < FOUT) ? acc[4 * g + 0 < FOUT ? 4 * g + 0 : 0] * dv : 0.0f;
        w.y = (4 * g + 1 < FOUT) ? acc[4 * g + 1 < FOUT ? 4 * g + 1 : 0] * dv : 0.0f;
        w.z = (4 * g + 2 < FOUT) ? acc[4 * g + 2 < FOUT ? 4 * g + 2 : 0] * dv : 0.0f;
        w.w = (4 * g + 3 < FOUT) ? acc[4 * g + 3 < FOUT ? 4 * g + 3 : 0] * dv : 0.0f;
        *reinterpret_cast<float4*>(ur + 4 * g) = w;
    }
}

// thread per (node, feature-quad): hout[n, 4g..4g+3] =
//   selu(dinv[n] * max(u[n], max_j u[src_j]) + b)
template <int FOUT, int SOUT>
__global__ void gather_max_selu_kernel(const float* __restrict__ u,
                                       const int* __restrict__ row_ptr,
                                       const int* __restrict__ sorted_src,
                                       const float* __restrict__ dinv,
                                       const float* __restrict__ b,
                                       float* __restrict__ hout,
                                       int N) {
    const int GP = SOUT / 4;
    int idx = blockIdx.x * blockDim.x + threadIdx.x;
    if (idx >= N * GP) return;
    int n = idx / GP;
    int g = idx - n * GP;
    const float* ur = u + (long long)n * SOUT + 4 * g;
    float4 acc = *reinterpret_cast<const float4*>(ur);  // self loop
    int j0 = row_ptr[n], j1 = row_ptr[n + 1];
    for (int j = j0; j < j1; ++j) {
        int s = sorted_src[j];
        float4 v = *reinterpret_cast<const float4*>(u + (long long)s * SOUT + 4 * g);
        acc.x = fmaxf(acc.x, v.x);
        acc.y = fmaxf(acc.y, v.y);
        acc.z = fmaxf(acc.z, v.z);
        acc.w = fmaxf(acc.w, v.w);
    }
    float dv = dinv[n];
    float bb[4];
#pragma unroll
    for (int k = 0; k < 4; ++k) bb[k] = (4 * g + k < FOUT) ? b[4 * g + k] : 0.0f;
    float vv[4] = {dv * acc.x + bb[0], dv * acc.y + bb[1], dv * acc.z + bb[2], dv * acc.w + bb[3]};
    float4 o;
    float* op = &o.x;
#pragma unroll
    for (int k = 0; k < 4; ++k) {
        float v = vv[k];
        op[k] = (v > 0.0f) ? (SELU_SCALE * v) : (SELU_SCALE * SELU_ALPHA * (expf(v) - 1.0f));
    }
    *reinterpret_cast<float4*>(hout + (long long)n * SOUT + 4 * g) = o;
}

// ===================== pooling (segmented sum over sorted batch ids) =====================

__global__ void segstart_kernel(const int* __restrict__ batch, int* __restrict__ seg, int N, int G) {
    int g = blockIdx.x * blockDim.x + threadIdx.x;
    if (g > G) return;
    if (g == G) { seg[G] = N; return; }
    int lo = 0, hi = N;
    while (lo < hi) { int mid = (lo + hi) >> 1; if (batch[mid] < g) lo = mid + 1; else hi = mid; }
    seg[g] = lo;
}

__global__ void pool_kernel(const float* __restrict__ h,
                            const int* __restrict__ seg,
                            float* __restrict__ pooled,
                            int G) {
    int idx = blockIdx.x * blockDim.x + threadIdx.x;  // G * 9
    if (idx >= G * 9) return;
    int g = idx / 9;
    int t = idx - g * 9;
    int lo = seg[g], hi = seg[g + 1];
    float4 acc = make_float4(0.f, 0.f, 0.f, 0.f);
    for (int n = lo; n < hi; ++n) {
        float4 v = *reinterpret_cast<const float4*>(h + (long long)n * 36 + 4 * t);
        acc.x += v.x; acc.y += v.y; acc.z += v.z; acc.w += v.w;
    }
    *reinterpret_cast<float4*>(pooled + (long long)g * 36 + 4 * t) = acc;
}

// ===================== MLP head =====================

__global__ void mlp1_kernel(const float* __restrict__ pooled,
                            const float* __restrict__ lw1,
                            const float* __restrict__ lb1,
                            float* __restrict__ y1,
                            int G) {
    __shared__ float Ws[36 * 96];
    for (int i = threadIdx.x; i < 36 * 96; i += blockDim.x) Ws[i] = lw1[i];
    __syncthreads();
    int idx = blockIdx.x * blockDim.x + threadIdx.x;
    if (idx >= G * 96) return;
    int g = idx / 96;
    int j = idx - g * 96;
    const float* pr = pooled + (long long)g * 36;
    float acc = lb1[j];
#pragma unroll
    for (int k4 = 0; k4 < 9; ++k4) {
        float4 pv = *reinterpret_cast<const float4*>(pr + 4 * k4);
        acc += pv.x * Ws[(4 * k4 + 0) * 96 + j];
        acc += pv.y * Ws[(4 * k4 + 1) * 96 + j];
        acc += pv.z * Ws[(4 * k4 + 2) * 96 + j];
        acc += pv.w * Ws[(4 * k4 + 3) * 96 + j];
    }
    y1[idx] = fmaxf(acc, 0.0f);
}

__global__ void mlp2_kernel(const float* __restrict__ y1,
                            const float* __restrict__ lw2,
                            const float* __restrict__ lb2,
                            float* __restrict__ out,
                            int G) {
    __shared__ float Ws[96 * 27];
    for (int i = threadIdx.x; i < 96 * 27; i += blockDim.x) Ws[i] = lw2[i];
    __syncthreads();
    int idx = blockIdx.x * blockDim.x + threadIdx.x;
    if (idx >= G * 27) return;
    int g = idx / 27;
    int c = idx - g * 27;
    const float* yr = y1 + (long long)g * 96;
    float acc = lb2[c];
#pragma unroll
    for (int k4 = 0; k4 < 24; ++k4) {
        float4 yv = *reinterpret_cast<const float4*>(yr + 4 * k4);
        acc += yv.x * Ws[(4 * k4 + 0) * 27 + c];
        acc += yv.y * Ws[(4 * k4 + 1) * 27 + c];
        acc += yv.z * Ws[(4 * k4 + 2) * 27 + c];
        acc += yv.w * Ws[(4 * k4 + 3) * 27 + c];
    }
    out[idx] = fmaxf(acc, 0.0f);
}

// ===================== launch =====================

extern "C" void kernel_launch(void* const* d_in, const int* in_sizes, int n_in,
                              void* d_out, int out_size, void* d_ws, size_t ws_size,
                              hipStream_t stream) {
    const float* x     = (const float*)d_in[0];
    const int*   ei    = (const int*)d_in[1];
    const int*   batch = (const int*)d_in[2];
    const float* W1  = (const float*)d_in[4];
    const float* b1  = (const float*)d_in[5];
    const float* W2  = (const float*)d_in[6];
    const float* b2  = (const float*)d_in[7];
    const float* W3  = (const float*)d_in[8];
    const float* b3  = (const float*)d_in[9];
    const float* W4  = (const float*)d_in[10];
    const float* b4  = (const float*)d_in[11];
    const float* lw1 = (const float*)d_in[12];
    const float* lb1 = (const float*)d_in[13];
    const float* lw2 = (const float*)d_in[14];
    const float* lb2 = (const float*)d_in[15];
    float* out = (float*)d_out;

    const int N = in_sizes[0] / 75;
    const int E = in_sizes[1] / 2;
    const int G = out_size / 27;
    const int* srcp = ei;
    const int* dstp = ei + E;

    // workspace carve-up
    char* ws = (char*)d_ws;
    size_t off = 0;
    auto carve = [&](size_t bytes) -> char* {
        char* p = ws + off;
        off = (off + bytes + 255) & ~(size_t)255;
        return p;
    };
    int*   cnt        = (int*)carve((size_t)N * 4);          // histogram, later cursor
    int*   row_ptr    = (int*)carve((size_t)(N + 1) * 4);
    int*   sorted_src = (int*)carve((size_t)E * 4);
    int*   bsum       = (int*)carve((size_t)cdiv(N, 1024) * 4 + 4);
    int*   seg        = (int*)carve((size_t)(G + 1) * 4);
    float* dinv       = (float*)carve((size_t)N * 4);
    float* A          = (float*)carve((size_t)N * 36 * 4);   // activations (padded strides <= 36)
    float* B          = (float*)carve((size_t)N * 36 * 4);   // u = (h@W)*dinv
    float* pooled     = (float*)carve((size_t)G * 36 * 4);
    float* y1         = (float*)carve((size_t)G * 96 * 4);
    (void)ws_size; (void)n_in;

    const int BLK = 256;
    const int nb = cdiv(N, 1024);

    // ---- edge preprocessing: histogram -> dinv -> scan -> CSR fill ----
    zero_int_kernel<<<cdiv(N, BLK), BLK, 0, stream>>>(cnt, N);
    hist_kernel<<<cdiv(E, BLK), BLK, 0, stream>>>(dstp, cnt, E);
    dinv_kernel<<<cdiv(N, BLK), BLK, 0, stream>>>(cnt, dinv, N);
    scan_partial_kernel<<<nb, 256, 0, stream>>>(cnt, bsum, N);
    scan_bsum_kernel<<<1, 64, 0, stream>>>(bsum, nb);
    scan_final_kernel<<<nb, 256, 0, stream>>>(cnt, bsum, row_ptr, N, E);
    zero_int_kernel<<<cdiv(N, BLK), BLK, 0, stream>>>(cnt, N);  // cursor
    fill_sorted_kernel<<<cdiv(E, BLK), BLK, 0, stream>>>(srcp, dstp, row_ptr, cnt, sorted_src, E);
    segstart_kernel<<<cdiv(G + 1, BLK), BLK, 0, stream>>>(batch, seg, N, G);

    // ---- layer 1: 75 -> 15 (stride 75 -> 16) ----
    gemm_scale_kernel<75, 75, 15, 16, false><<<cdiv(N, BLK), BLK, 0, stream>>>(x, W1, dinv, B, N);
    gather_max_selu_kernel<15, 16><<<cdiv((long long)N * 4, BLK), BLK, 0, stream>>>(B, row_ptr, sorted_src, dinv, b1, A, N);

    // ---- layer 2: 15 -> 20 (stride 16 -> 20) ----
    gemm_scale_kernel<15, 16, 20, 20, true><<<cdiv(N, BLK), BLK, 0, stream>>>(A, W2, dinv, B, N);
    gather_max_selu_kernel<20, 20><<<cdiv((long long)N * 5, BLK), BLK, 0, stream>>>(B, row_ptr, sorted_src, dinv, b2, A, N);

    // ---- layer 3: 20 -> 27 (stride 20 -> 28) ----
    gemm_scale_kernel<20, 20, 27, 28, true><<<cdiv(N, BLK), BLK, 0, stream>>>(A, W3, dinv, B, N);
    gather_max_selu_kernel<27, 28><<<cdiv((long long)N * 7, BLK), BLK, 0, stream>>>(B, row_ptr, sorted_src, dinv, b3, A, N);

    // ---- layer 4: 27 -> 36 (stride 28 -> 36) ----
    gemm_scale_kernel<27, 28, 36, 36, true><<<cdiv(N, BLK), BLK, 0, stream>>>(A, W4, dinv, B, N);
    gather_max_selu_kernel<36, 36><<<cdiv((long long)N * 9, BLK), BLK, 0, stream>>>(B, row_ptr, sorted_src, dinv, b4, A, N);

    // ---- pool: segmented sum (batch_vec is sorted) ----
    pool_kernel<<<cdiv((long long)G * 9, BLK), BLK, 0, stream>>>(A, seg, pooled, G);

    // ---- MLP head ----
    mlp1_kernel<<<cdiv((long long)G * 96, BLK), BLK, 0, stream>>>(pooled, lw1, lb1, y1, G);
    mlp2_kernel<<<cdiv((long long)G * 27, BLK), BLK, 0, stream>>>(y1, lw2, lb2, out, G);
}

// Round 4
// 1375.259 us; speedup vs baseline: 12.4019x; 1.0657x over previous
//
#include <hip/hip_runtime.h>
#include <math.h>

#define SELU_SCALE 1.0507009873554805f
#define SELU_ALPHA 1.6732632423543772f

static inline int cdiv(long long a, int b) { return (int)((a + b - 1) / b); }

// ===================== edge preprocessing (once, reused by all layers) =====================

__global__ void zero_int_kernel(int* __restrict__ p, int n) {
    int i = blockIdx.x * blockDim.x + threadIdx.x;
    if (i < n) p[i] = 0;
}

__global__ void hist_kernel(const int* __restrict__ dst, int* __restrict__ cnt, int E) {
    int e = blockIdx.x * blockDim.x + threadIdx.x;
    if (e < E) atomicAdd(&cnt[dst[e]], 1);
}

__global__ void dinv_kernel(const int* __restrict__ cnt, float* __restrict__ dinv, int N) {
    int i = blockIdx.x * blockDim.x + threadIdx.x;
    if (i < N) dinv[i] = rsqrtf((float)cnt[i] + 1.0f);  // +1 self loop
}

// ---- 3-phase exclusive scan of cnt[0..N) -> row_ptr (+ cursor copy), chunk = 1024/block ----
__global__ void scan_partial_kernel(const int* __restrict__ cnt, int* __restrict__ bsum, int N) {
    __shared__ int sh[256];
    int base = blockIdx.x * 1024;
    int t = threadIdx.x;
    int s = 0;
#pragma unroll
    for (int k = 0; k < 4; ++k) {
        int i = base + t * 4 + k;
        if (i < N) s += cnt[i];
    }
    sh[t] = s;
    __syncthreads();
    for (int o = 128; o > 0; o >>= 1) {
        if (t < o) sh[t] += sh[t + o];
        __syncthreads();
    }
    if (t == 0) bsum[blockIdx.x] = sh[0];
}

// single-block parallel exclusive scan of bsum (nb <= 1024)
__global__ void scan_bsum_par_kernel(int* __restrict__ bsum, int nb) {
    __shared__ int sh[1024];
    int t = threadIdx.x;
    int v = (t < nb) ? bsum[t] : 0;
    sh[t] = v;
    __syncthreads();
    for (int o = 1; o < 1024; o <<= 1) {
        int y = (t >= o) ? sh[t - o] : 0;
        __syncthreads();
        sh[t] += y;
        __syncthreads();
    }
    if (t < nb) bsum[t] = sh[t] - v;
}

__global__ void scan_bsum_serial_kernel(int* __restrict__ bsum, int nb) {
    if (blockIdx.x == 0 && threadIdx.x == 0) {
        int acc = 0;
        for (int i = 0; i < nb; ++i) { int v = bsum[i]; bsum[i] = acc; acc += v; }
    }
}

// writes row_ptr AND re-purposes cnt as the fill cursor (cnt[i] = row start)
__global__ void scan_final_kernel(int* __restrict__ cnt, const int* __restrict__ bsum,
                                  int* __restrict__ row_ptr, int N, int E) {
    __shared__ int sh[256];
    int base = blockIdx.x * 1024;
    int t = threadIdx.x;
    int i0 = base + t * 4;
    int v0 = (i0 + 0 < N) ? cnt[i0 + 0] : 0;
    int v1 = (i0 + 1 < N) ? cnt[i0 + 1] : 0;
    int v2 = (i0 + 2 < N) ? cnt[i0 + 2] : 0;
    int v3 = (i0 + 3 < N) ? cnt[i0 + 3] : 0;
    sh[t] = v0 + v1 + v2 + v3;
    __syncthreads();
    for (int o = 1; o < 256; o <<= 1) {
        int y = (t >= o) ? sh[t - o] : 0;
        __syncthreads();
        sh[t] += y;
        __syncthreads();
    }
    int off = bsum[blockIdx.x] + ((t > 0) ? sh[t - 1] : 0);
    if (i0 + 0 < N) { row_ptr[i0 + 0] = off; cnt[i0 + 0] = off; }  off += v0;
    if (i0 + 1 < N) { row_ptr[i0 + 1] = off; cnt[i0 + 1] = off; }  off += v1;
    if (i0 + 2 < N) { row_ptr[i0 + 2] = off; cnt[i0 + 2] = off; }  off += v2;
    if (i0 + 3 < N) { row_ptr[i0 + 3] = off; cnt[i0 + 3] = off; }
    if (blockIdx.x == 0 && t == 0) row_ptr[N] = E;
}

// cursor[] pre-initialized to row starts -> atomicAdd yields final position directly
__global__ void fill_sorted_kernel(const int* __restrict__ src, const int* __restrict__ dst,
                                   int* __restrict__ cursor,
                                   int* __restrict__ sorted_src, int E) {
    int e = blockIdx.x * blockDim.x + threadIdx.x;
    if (e >= E) return;
    int pos = atomicAdd(&cursor[dst[e]], 1);
    sorted_src[pos] = src[e];
}

// ===================== layer kernels =====================

// layer-1 GEMM: u1[n,:] = (x[n,:] @ W1) * dinv[n]  (scalar input loads, stride 75)
template <int FIN, int SIN, int FOUT, int SOUT>
__global__ void gemm_scale_kernel(const float* __restrict__ h,
                                  const float* __restrict__ W,
                                  const float* __restrict__ dinv,
                                  float* __restrict__ u,
                                  int N) {
    int n = blockIdx.x * blockDim.x + threadIdx.x;
    if (n >= N) return;
    const float* hr = h + (long long)n * SIN;
    float acc[FOUT];
#pragma unroll
    for (int c = 0; c < FOUT; ++c) acc[c] = 0.0f;
#pragma unroll
    for (int fi = 0; fi < FIN; ++fi) {
        float hv = hr[fi];
#pragma unroll
        for (int c = 0; c < FOUT; ++c) acc[c] += hv * W[fi * FOUT + c];
    }
    float dv = dinv[n];
    float* ur = u + (long long)n * SOUT;
#pragma unroll
    for (int g = 0; g < SOUT / 4; ++g) {
        float4 w;
        w.x = (4 * g + 0 < FOUT) ? acc[(4 * g + 0 < FOUT) ? 4 * g + 0 : 0] * dv : 0.0f;
        w.y = (4 * g + 1 < FOUT) ? acc[(4 * g + 1 < FOUT) ? 4 * g + 1 : 0] * dv : 0.0f;
        w.z = (4 * g + 2 < FOUT) ? acc[(4 * g + 2 < FOUT) ? 4 * g + 2 : 0] * dv : 0.0f;
        w.w = (4 * g + 3 < FOUT) ? acc[(4 * g + 3 < FOUT) ? 4 * g + 3 : 0] * dv : 0.0f;
        *reinterpret_cast<float4*>(ur + 4 * g) = w;
    }
}

// fused: h[n] = selu(dinv*max(u[n],max_j u[src_j]) + bprev); uout[n] = (h @ W)*dinv[n]
// one thread per node; everything in registers, W/b at wave-uniform indices -> s_load.
template <int SPREV, int FPREV, int FOUT, int SOUT>
__global__ void agg_gemm_kernel(const float* __restrict__ u,
                                const int* __restrict__ row_ptr,
                                const int* __restrict__ sorted_src,
                                const float* __restrict__ dinv,
                                const float* __restrict__ bprev,
                                const float* __restrict__ W,
                                float* __restrict__ uout,
                                int N) {
    int n = blockIdx.x * blockDim.x + threadIdx.x;
    if (n >= N) return;
    constexpr int GPQ = SPREV / 4;
    const float* ur = u + (long long)n * SPREV;
    float4 acc[GPQ];
#pragma unroll
    for (int q = 0; q < GPQ; ++q) acc[q] = *reinterpret_cast<const float4*>(ur + 4 * q);
    int j0 = row_ptr[n], j1 = row_ptr[n + 1];
    for (int j = j0; j < j1; ++j) {
        int s = sorted_src[j];
        const float* sr = u + (long long)s * SPREV;
#pragma unroll
        for (int q = 0; q < GPQ; ++q) {
            float4 v = *reinterpret_cast<const float4*>(sr + 4 * q);
            acc[q].x = fmaxf(acc[q].x, v.x);
            acc[q].y = fmaxf(acc[q].y, v.y);
            acc[q].z = fmaxf(acc[q].z, v.z);
            acc[q].w = fmaxf(acc[q].w, v.w);
        }
    }
    float dv = dinv[n];
    float h[FPREV];
#pragma unroll
    for (int q = 0; q < GPQ; ++q) {
        float vals[4] = {acc[q].x, acc[q].y, acc[q].z, acc[q].w};
#pragma unroll
        for (int k = 0; k < 4; ++k) {
            constexpr int dummy = 0; (void)dummy;
            int f = 4 * q + k;
            if (f < FPREV) {
                float v = dv * vals[k] + bprev[f];
                h[f] = (v > 0.0f) ? (SELU_SCALE * v) : (SELU_SCALE * SELU_ALPHA * (expf(v) - 1.0f));
            }
        }
    }
    float out[FOUT];
#pragma unroll
    for (int c = 0; c < FOUT; ++c) out[c] = 0.0f;
#pragma unroll
    for (int fi = 0; fi < FPREV; ++fi) {
        float hv = h[fi];
#pragma unroll
        for (int c = 0; c < FOUT; ++c) out[c] += hv * W[fi * FOUT + c];
    }
    float* op = uout + (long long)n * SOUT;
#pragma unroll
    for (int g = 0; g < SOUT / 4; ++g) {
        float4 w;
        w.x = (4 * g + 0 < FOUT) ? out[(4 * g + 0 < FOUT) ? 4 * g + 0 : 0] * dv : 0.0f;
        w.y = (4 * g + 1 < FOUT) ? out[(4 * g + 1 < FOUT) ? 4 * g + 1 : 0] * dv : 0.0f;
        w.z = (4 * g + 2 < FOUT) ? out[(4 * g + 2 < FOUT) ? 4 * g + 2 : 0] * dv : 0.0f;
        w.w = (4 * g + 3 < FOUT) ? out[(4 * g + 3 < FOUT) ? 4 * g + 3 : 0] * dv : 0.0f;
        *reinterpret_cast<float4*>(op + 4 * g) = w;
    }
}

// final aggregation (layer 4): quad-parallel, writes h4
template <int FOUT, int SOUT>
__global__ void gather_max_selu_kernel(const float* __restrict__ u,
                                       const int* __restrict__ row_ptr,
                                       const int* __restrict__ sorted_src,
                                       const float* __restrict__ dinv,
                                       const float* __restrict__ b,
                                       float* __restrict__ hout,
                                       int N) {
    const int GP = SOUT / 4;
    int idx = blockIdx.x * blockDim.x + threadIdx.x;
    if (idx >= N * GP) return;
    int n = idx / GP;
    int g = idx - n * GP;
    const float* ur = u + (long long)n * SOUT + 4 * g;
    float4 acc = *reinterpret_cast<const float4*>(ur);  // self loop
    int j0 = row_ptr[n], j1 = row_ptr[n + 1];
    for (int j = j0; j < j1; ++j) {
        int s = sorted_src[j];
        float4 v = *reinterpret_cast<const float4*>(u + (long long)s * SOUT + 4 * g);
        acc.x = fmaxf(acc.x, v.x);
        acc.y = fmaxf(acc.y, v.y);
        acc.z = fmaxf(acc.z, v.z);
        acc.w = fmaxf(acc.w, v.w);
    }
    float dv = dinv[n];
    float bb[4];
#pragma unroll
    for (int k = 0; k < 4; ++k) bb[k] = (4 * g + k < FOUT) ? b[4 * g + k] : 0.0f;
    float vv[4] = {dv * acc.x + bb[0], dv * acc.y + bb[1], dv * acc.z + bb[2], dv * acc.w + bb[3]};
    float4 o;
    float* op = &o.x;
#pragma unroll
    for (int k = 0; k < 4; ++k) {
        float v = vv[k];
        op[k] = (v > 0.0f) ? (SELU_SCALE * v) : (SELU_SCALE * SELU_ALPHA * (expf(v) - 1.0f));
    }
    *reinterpret_cast<float4*>(hout + (long long)n * SOUT + 4 * g) = o;
}

// ===================== pooling (segmented sum over sorted batch ids) =====================

__global__ void segstart_kernel(const int* __restrict__ batch, int* __restrict__ seg, int N, int G) {
    int g = blockIdx.x * blockDim.x + threadIdx.x;
    if (g > G) return;
    if (g == G) { seg[G] = N; return; }
    int lo = 0, hi = N;
    while (lo < hi) { int mid = (lo + hi) >> 1; if (batch[mid] < g) lo = mid + 1; else hi = mid; }
    seg[g] = lo;
}

__global__ void pool_kernel(const float* __restrict__ h,
                            const int* __restrict__ seg,
                            float* __restrict__ pooled,
                            int G) {
    int idx = blockIdx.x * blockDim.x + threadIdx.x;  // G * 9
    if (idx >= G * 9) return;
    int g = idx / 9;
    int t = idx - g * 9;
    int lo = seg[g], hi = seg[g + 1];
    float4 acc = make_float4(0.f, 0.f, 0.f, 0.f);
    for (int n = lo; n < hi; ++n) {
        float4 v = *reinterpret_cast<const float4*>(h + (long long)n * 36 + 4 * t);
        acc.x += v.x; acc.y += v.y; acc.z += v.z; acc.w += v.w;
    }
    *reinterpret_cast<float4*>(pooled + (long long)g * 36 + 4 * t) = acc;
}

// ===================== MLP head =====================

__global__ void mlp1_kernel(const float* __restrict__ pooled,
                            const float* __restrict__ lw1,
                            const float* __restrict__ lb1,
                            float* __restrict__ y1,
                            int G) {
    __shared__ float Ws[36 * 96];
    for (int i = threadIdx.x; i < 36 * 96; i += blockDim.x) Ws[i] = lw1[i];
    __syncthreads();
    int idx = blockIdx.x * blockDim.x + threadIdx.x;
    if (idx >= G * 96) return;
    int g = idx / 96;
    int j = idx - g * 96;
    const float* pr = pooled + (long long)g * 36;
    float acc = lb1[j];
#pragma unroll
    for (int k4 = 0; k4 < 9; ++k4) {
        float4 pv = *reinterpret_cast<const float4*>(pr + 4 * k4);
        acc += pv.x * Ws[(4 * k4 + 0) * 96 + j];
        acc += pv.y * Ws[(4 * k4 + 1) * 96 + j];
        acc += pv.z * Ws[(4 * k4 + 2) * 96 + j];
        acc += pv.w * Ws[(4 * k4 + 3) * 96 + j];
    }
    y1[idx] = fmaxf(acc, 0.0f);
}

__global__ void mlp2_kernel(const float* __restrict__ y1,
                            const float* __restrict__ lw2,
                            const float* __restrict__ lb2,
                            float* __restrict__ out,
                            int G) {
    __shared__ float Ws[96 * 27];
    for (int i = threadIdx.x; i < 96 * 27; i += blockDim.x) Ws[i] = lw2[i];
    __syncthreads();
    int idx = blockIdx.x * blockDim.x + threadIdx.x;
    if (idx >= G * 27) return;
    int g = idx / 27;
    int c = idx - g * 27;
    const float* yr = y1 + (long long)g * 96;
    float acc = lb2[c];
#pragma unroll
    for (int k4 = 0; k4 < 24; ++k4) {
        float4 yv = *reinterpret_cast<const float4*>(yr + 4 * k4);
        acc += yv.x * Ws[(4 * k4 + 0) * 27 + c];
        acc += yv.y * Ws[(4 * k4 + 1) * 27 + c];
        acc += yv.z * Ws[(4 * k4 + 2) * 27 + c];
        acc += yv.w * Ws[(4 * k4 + 3) * 27 + c];
    }
    out[idx] = fmaxf(acc, 0.0f);
}

// ===================== launch =====================

extern "C" void kernel_launch(void* const* d_in, const int* in_sizes, int n_in,
                              void* d_out, int out_size, void* d_ws, size_t ws_size,
                              hipStream_t stream) {
    const float* x     = (const float*)d_in[0];
    const int*   ei    = (const int*)d_in[1];
    const int*   batch = (const int*)d_in[2];
    const float* W1  = (const float*)d_in[4];
    const float* b1  = (const float*)d_in[5];
    const float* W2  = (const float*)d_in[6];
    const float* b2  = (const float*)d_in[7];
    const float* W3  = (const float*)d_in[8];
    const float* b3  = (const float*)d_in[9];
    const float* W4  = (const float*)d_in[10];
    const float* b4  = (const float*)d_in[11];
    const float* lw1 = (const float*)d_in[12];
    const float* lb1 = (const float*)d_in[13];
    const float* lw2 = (const float*)d_in[14];
    const float* lb2 = (const float*)d_in[15];
    float* out = (float*)d_out;

    const int N = in_sizes[0] / 75;
    const int E = in_sizes[1] / 2;
    const int G = out_size / 27;
    const int* srcp = ei;
    const int* dstp = ei + E;

    // workspace carve-up
    char* ws = (char*)d_ws;
    size_t off = 0;
    auto carve = [&](size_t bytes) -> char* {
        char* p = ws + off;
        off = (off + bytes + 255) & ~(size_t)255;
        return p;
    };
    int*   cnt        = (int*)carve((size_t)N * 4);          // histogram -> cursor
    int*   row_ptr    = (int*)carve((size_t)(N + 1) * 4);
    int*   sorted_src = (int*)carve((size_t)E * 4);
    int*   bsum       = (int*)carve((size_t)cdiv(N, 1024) * 4 + 4);
    int*   seg        = (int*)carve((size_t)(G + 1) * 4);
    float* dinv       = (float*)carve((size_t)N * 4);
    float* A          = (float*)carve((size_t)N * 36 * 4);   // ping-pong buffers
    float* B          = (float*)carve((size_t)N * 36 * 4);
    float* pooled     = (float*)carve((size_t)G * 36 * 4);
    float* y1         = (float*)carve((size_t)G * 96 * 4);
    (void)ws_size; (void)n_in;

    const int BLK = 256;
    const int nb = cdiv(N, 1024);

    // ---- edge preprocessing: histogram -> dinv -> scan(+cursor) -> CSR fill ----
    zero_int_kernel<<<cdiv(N, BLK), BLK, 0, stream>>>(cnt, N);
    hist_kernel<<<cdiv(E, BLK), BLK, 0, stream>>>(dstp, cnt, E);
    dinv_kernel<<<cdiv(N, BLK), BLK, 0, stream>>>(cnt, dinv, N);
    scan_partial_kernel<<<nb, 256, 0, stream>>>(cnt, bsum, N);
    if (nb <= 1024) scan_bsum_par_kernel<<<1, 1024, 0, stream>>>(bsum, nb);
    else            scan_bsum_serial_kernel<<<1, 64, 0, stream>>>(bsum, nb);
    scan_final_kernel<<<nb, 256, 0, stream>>>(cnt, bsum, row_ptr, N, E);
    fill_sorted_kernel<<<cdiv(E, BLK), BLK, 0, stream>>>(srcp, dstp, cnt, sorted_src, E);
    segstart_kernel<<<cdiv(G + 1, BLK), BLK, 0, stream>>>(batch, seg, N, G);

    // strides: u1=16 (64B rows), u2=20 (80B), u3=32 (128B, line-aligned), u4=36
    // ---- layer 1 GEMM: x @ W1 -> u1 (B) ----
    gemm_scale_kernel<75, 75, 15, 16><<<cdiv(N, BLK), BLK, 0, stream>>>(x, W1, dinv, B, N);
    // ---- fused agg1 + gemm2: u1 -> u2 (A) ----
    agg_gemm_kernel<16, 15, 20, 20><<<cdiv(N, BLK), BLK, 0, stream>>>(B, row_ptr, sorted_src, dinv, b1, W2, A, N);
    // ---- fused agg2 + gemm3: u2 -> u3 (B) ----
    agg_gemm_kernel<20, 20, 27, 32><<<cdiv(N, BLK), BLK, 0, stream>>>(A, row_ptr, sorted_src, dinv, b2, W3, B, N);
    // ---- fused agg3 + gemm4: u3 -> u4 (A) ----
    agg_gemm_kernel<32, 27, 36, 36><<<cdiv(N, BLK), BLK, 0, stream>>>(B, row_ptr, sorted_src, dinv, b3, W4, A, N);
    // ---- final agg4: u4 -> h4 (B, stride 36) ----
    gather_max_selu_kernel<36, 36><<<cdiv((long long)N * 9, BLK), BLK, 0, stream>>>(A, row_ptr, sorted_src, dinv, b4, B, N);

    // ---- pool: segmented sum (batch_vec is sorted) ----
    pool_kernel<<<cdiv((long long)G * 9, BLK), BLK, 0, stream>>>(B, seg, pooled, G);

    // ---- MLP head ----
    mlp1_kernel<<<cdiv((long long)G * 96, BLK), BLK, 0, stream>>>(pooled, lw1, lb1, y1, G);
    mlp2_kernel<<<cdiv((long long)G * 27, BLK), BLK, 0, stream>>>(y1, lw2, lb2, out, G);
}

// Round 5
// 1320.349 us; speedup vs baseline: 12.9177x; 1.0416x over previous
//
#include <hip/hip_runtime.h>
#include <math.h>

#define SELU_SCALE 1.0507009873554805f
#define SELU_ALPHA 1.6732632423543772f

static inline int cdiv(long long a, int b) { return (int)((a + b - 1) / b); }

// ===================== edge preprocessing (once, reused by all layers) =====================

__global__ void zero_int_kernel(int* __restrict__ p, int n) {
    int i = blockIdx.x * blockDim.x + threadIdx.x;
    if (i < n) p[i] = 0;
}

// 4 edges/thread histogram: 4 independent atomics in flight
__global__ void hist4_kernel(const int* __restrict__ dst, int* __restrict__ cnt, int E) {
    int i = blockIdx.x * blockDim.x + threadIdx.x;
    int base = i * 4;
    if (base + 3 < E) {
        int4 d = *reinterpret_cast<const int4*>(dst + base);
        atomicAdd(&cnt[d.x], 1);
        atomicAdd(&cnt[d.y], 1);
        atomicAdd(&cnt[d.z], 1);
        atomicAdd(&cnt[d.w], 1);
    } else {
        for (int e = base; e < E; ++e) atomicAdd(&cnt[dst[e]], 1);
    }
}

__global__ void dinv_kernel(const int* __restrict__ cnt, float* __restrict__ dinv, int N) {
    int i = blockIdx.x * blockDim.x + threadIdx.x;
    if (i < N) dinv[i] = rsqrtf((float)cnt[i] + 1.0f);  // +1 self loop
}

// ---- 3-phase exclusive scan of cnt[0..N) -> row_ptr, chunk = 1024/block ----
__global__ void scan_partial_kernel(const int* __restrict__ cnt, int* __restrict__ bsum, int N) {
    __shared__ int sh[256];
    int base = blockIdx.x * 1024;
    int t = threadIdx.x;
    int s = 0;
#pragma unroll
    for (int k = 0; k < 4; ++k) {
        int i = base + t * 4 + k;
        if (i < N) s += cnt[i];
    }
    sh[t] = s;
    __syncthreads();
    for (int o = 128; o > 0; o >>= 1) {
        if (t < o) sh[t] += sh[t + o];
        __syncthreads();
    }
    if (t == 0) bsum[blockIdx.x] = sh[0];
}

__global__ void scan_bsum_par_kernel(int* __restrict__ bsum, int nb) {
    __shared__ int sh[1024];
    int t = threadIdx.x;
    int v = (t < nb) ? bsum[t] : 0;
    sh[t] = v;
    __syncthreads();
    for (int o = 1; o < 1024; o <<= 1) {
        int y = (t >= o) ? sh[t - o] : 0;
        __syncthreads();
        sh[t] += y;
        __syncthreads();
    }
    if (t < nb) bsum[t] = sh[t] - v;
}

__global__ void scan_bsum_serial_kernel(int* __restrict__ bsum, int nb) {
    if (blockIdx.x == 0 && threadIdx.x == 0) {
        int acc = 0;
        for (int i = 0; i < nb; ++i) { int v = bsum[i]; bsum[i] = acc; acc += v; }
    }
}

__global__ void scan_final_kernel(const int* __restrict__ cnt, const int* __restrict__ bsum,
                                  int* __restrict__ row_ptr, int N, int E) {
    __shared__ int sh[256];
    int base = blockIdx.x * 1024;
    int t = threadIdx.x;
    int i0 = base + t * 4;
    int v0 = (i0 + 0 < N) ? cnt[i0 + 0] : 0;
    int v1 = (i0 + 1 < N) ? cnt[i0 + 1] : 0;
    int v2 = (i0 + 2 < N) ? cnt[i0 + 2] : 0;
    int v3 = (i0 + 3 < N) ? cnt[i0 + 3] : 0;
    sh[t] = v0 + v1 + v2 + v3;
    __syncthreads();
    for (int o = 1; o < 256; o <<= 1) {
        int y = (t >= o) ? sh[t - o] : 0;
        __syncthreads();
        sh[t] += y;
        __syncthreads();
    }
    int off = bsum[blockIdx.x] + ((t > 0) ? sh[t - 1] : 0);
    if (i0 + 0 < N) row_ptr[i0 + 0] = off;  off += v0;
    if (i0 + 1 < N) row_ptr[i0 + 1] = off;  off += v1;
    if (i0 + 2 < N) row_ptr[i0 + 2] = off;  off += v2;
    if (i0 + 3 < N) row_ptr[i0 + 3] = off;
    if (blockIdx.x == 0 && t == 0) row_ptr[N] = E;
}

// R3-style (row_ptr read || zeroed-cursor atomic), 4 edges/thread for MLP
__global__ void fill_sorted4_kernel(const int* __restrict__ src, const int* __restrict__ dst,
                                    const int* __restrict__ row_ptr, int* __restrict__ cursor,
                                    int* __restrict__ sorted_src, int E) {
    int i = blockIdx.x * blockDim.x + threadIdx.x;
    int base = i * 4;
    if (base + 3 < E) {
        int4 d = *reinterpret_cast<const int4*>(dst + base);
        int4 s = *reinterpret_cast<const int4*>(src + base);
        int r0 = row_ptr[d.x];
        int r1 = row_ptr[d.y];
        int r2 = row_ptr[d.z];
        int r3 = row_ptr[d.w];
        int k0 = atomicAdd(&cursor[d.x], 1);
        int k1 = atomicAdd(&cursor[d.y], 1);
        int k2 = atomicAdd(&cursor[d.z], 1);
        int k3 = atomicAdd(&cursor[d.w], 1);
        sorted_src[r0 + k0] = s.x;
        sorted_src[r1 + k1] = s.y;
        sorted_src[r2 + k2] = s.z;
        sorted_src[r3 + k3] = s.w;
    } else {
        for (int e = base; e < E; ++e) {
            int dd = dst[e];
            int pos = row_ptr[dd] + atomicAdd(&cursor[dd], 1);
            sorted_src[pos] = src[e];
        }
    }
}

// ===================== layer kernels =====================

// layer-1 GEMM: u1[n,:] = (x[n,:] @ W1) * dinv[n]
template <int FIN, int SIN, int FOUT, int SOUT>
__global__ void gemm_scale_kernel(const float* __restrict__ h,
                                  const float* __restrict__ W,
                                  const float* __restrict__ dinv,
                                  float* __restrict__ u,
                                  int N) {
    int n = blockIdx.x * blockDim.x + threadIdx.x;
    if (n >= N) return;
    const float* hr = h + (long long)n * SIN;
    float acc[FOUT];
#pragma unroll
    for (int c = 0; c < FOUT; ++c) acc[c] = 0.0f;
#pragma unroll
    for (int fi = 0; fi < FIN; ++fi) {
        float hv = hr[fi];
#pragma unroll
        for (int c = 0; c < FOUT; ++c) acc[c] += hv * W[fi * FOUT + c];
    }
    float dv = dinv[n];
    float* ur = u + (long long)n * SOUT;
#pragma unroll
    for (int g = 0; g < SOUT / 4; ++g) {
        float4 w;
        w.x = (4 * g + 0 < FOUT) ? acc[(4 * g + 0 < FOUT) ? 4 * g + 0 : 0] * dv : 0.0f;
        w.y = (4 * g + 1 < FOUT) ? acc[(4 * g + 1 < FOUT) ? 4 * g + 1 : 0] * dv : 0.0f;
        w.z = (4 * g + 2 < FOUT) ? acc[(4 * g + 2 < FOUT) ? 4 * g + 2 : 0] * dv : 0.0f;
        w.w = (4 * g + 3 < FOUT) ? acc[(4 * g + 3 < FOUT) ? 4 * g + 3 : 0] * dv : 0.0f;
        *reinterpret_cast<float4*>(ur + 4 * g) = w;
    }
}

template <int GPQ>
__device__ __forceinline__ void fmax4_row(float4* __restrict__ acc, const float* __restrict__ row) {
#pragma unroll
    for (int q = 0; q < GPQ; ++q) {
        float4 v = *reinterpret_cast<const float4*>(row + 4 * q);
        acc[q].x = fmaxf(acc[q].x, v.x);
        acc[q].y = fmaxf(acc[q].y, v.y);
        acc[q].z = fmaxf(acc[q].z, v.z);
        acc[q].w = fmaxf(acc[q].w, v.w);
    }
}

// fused: h = selu(dinv*max(...) + bprev); uout = (h @ W)*dinv  — thread per node
template <int SPREV, int FPREV, int FOUT, int SOUT>
__global__ void agg_gemm_kernel(const float* __restrict__ u,
                                const int* __restrict__ row_ptr,
                                const int* __restrict__ sorted_src,
                                const float* __restrict__ dinv,
                                const float* __restrict__ bprev,
                                const float* __restrict__ W,
                                float* __restrict__ uout,
                                int N) {
    int n = blockIdx.x * blockDim.x + threadIdx.x;
    if (n >= N) return;
    constexpr int GPQ = SPREV / 4;
    const float* ur = u + (long long)n * SPREV;
    float4 acc[GPQ];
#pragma unroll
    for (int q = 0; q < GPQ; ++q) acc[q] = *reinterpret_cast<const float4*>(ur + 4 * q);
    int j0 = row_ptr[n], j1 = row_ptr[n + 1];
    int j = j0;
    for (; j + 1 < j1; j += 2) {  // two independent row loads in flight
        const float* r0 = u + (long long)sorted_src[j] * SPREV;
        const float* r1 = u + (long long)sorted_src[j + 1] * SPREV;
        fmax4_row<GPQ>(acc, r0);
        fmax4_row<GPQ>(acc, r1);
    }
    if (j < j1) fmax4_row<GPQ>(acc, u + (long long)sorted_src[j] * SPREV);

    float dv = dinv[n];
    float h[FPREV];
#pragma unroll
    for (int q = 0; q < GPQ; ++q) {
        float vals[4] = {acc[q].x, acc[q].y, acc[q].z, acc[q].w};
#pragma unroll
        for (int k = 0; k < 4; ++k) {
            int f = 4 * q + k;
            if (f < FPREV) {
                float v = dv * vals[k] + bprev[f];
                h[f] = (v > 0.0f) ? (SELU_SCALE * v) : (SELU_SCALE * SELU_ALPHA * (expf(v) - 1.0f));
            }
        }
    }
    float out[FOUT];
#pragma unroll
    for (int c = 0; c < FOUT; ++c) out[c] = 0.0f;
#pragma unroll
    for (int fi = 0; fi < FPREV; ++fi) {
        float hv = h[fi];
#pragma unroll
        for (int c = 0; c < FOUT; ++c) out[c] += hv * W[fi * FOUT + c];
    }
    float* op = uout + (long long)n * SOUT;
#pragma unroll
    for (int g = 0; g < SOUT / 4; ++g) {
        float4 w;
        w.x = (4 * g + 0 < FOUT) ? out[(4 * g + 0 < FOUT) ? 4 * g + 0 : 0] * dv : 0.0f;
        w.y = (4 * g + 1 < FOUT) ? out[(4 * g + 1 < FOUT) ? 4 * g + 1 : 0] * dv : 0.0f;
        w.z = (4 * g + 2 < FOUT) ? out[(4 * g + 2 < FOUT) ? 4 * g + 2 : 0] * dv : 0.0f;
        w.w = (4 * g + 3 < FOUT) ? out[(4 * g + 3 < FOUT) ? 4 * g + 3 : 0] * dv : 0.0f;
        *reinterpret_cast<float4*>(op + 4 * g) = w;
    }
}

// final aggregation (layer 4): thread per node, index list read once
template <int S, int F>
__global__ void agg_selu_kernel(const float* __restrict__ u,
                                const int* __restrict__ row_ptr,
                                const int* __restrict__ sorted_src,
                                const float* __restrict__ dinv,
                                const float* __restrict__ b,
                                float* __restrict__ hout,
                                int N) {
    int n = blockIdx.x * blockDim.x + threadIdx.x;
    if (n >= N) return;
    constexpr int GPQ = S / 4;
    const float* ur = u + (long long)n * S;
    float4 acc[GPQ];
#pragma unroll
    for (int q = 0; q < GPQ; ++q) acc[q] = *reinterpret_cast<const float4*>(ur + 4 * q);
    int j0 = row_ptr[n], j1 = row_ptr[n + 1];
    int j = j0;
    for (; j + 1 < j1; j += 2) {
        const float* r0 = u + (long long)sorted_src[j] * S;
        const float* r1 = u + (long long)sorted_src[j + 1] * S;
        fmax4_row<GPQ>(acc, r0);
        fmax4_row<GPQ>(acc, r1);
    }
    if (j < j1) fmax4_row<GPQ>(acc, u + (long long)sorted_src[j] * S);

    float dv = dinv[n];
    float* op = hout + (long long)n * S;
#pragma unroll
    for (int q = 0; q < GPQ; ++q) {
        float vals[4] = {acc[q].x, acc[q].y, acc[q].z, acc[q].w};
        float4 o;
        float* ov = &o.x;
#pragma unroll
        for (int k = 0; k < 4; ++k) {
            int f = 4 * q + k;
            if (f < F) {
                float v = dv * vals[k] + b[f];
                ov[k] = (v > 0.0f) ? (SELU_SCALE * v) : (SELU_SCALE * SELU_ALPHA * (expf(v) - 1.0f));
            } else {
                ov[k] = 0.0f;
            }
        }
        *reinterpret_cast<float4*>(op + 4 * q) = o;
    }
}

// ===================== pooling (segmented sum over sorted batch ids) =====================

__global__ void segstart_kernel(const int* __restrict__ batch, int* __restrict__ seg, int N, int G) {
    int g = blockIdx.x * blockDim.x + threadIdx.x;
    if (g > G) return;
    if (g == G) { seg[G] = N; return; }
    int lo = 0, hi = N;
    while (lo < hi) { int mid = (lo + hi) >> 1; if (batch[mid] < g) lo = mid + 1; else hi = mid; }
    seg[g] = lo;
}

__global__ void pool_kernel(const float* __restrict__ h,
                            const int* __restrict__ seg,
                            float* __restrict__ pooled,
                            int G) {
    int idx = blockIdx.x * blockDim.x + threadIdx.x;  // G * 9
    if (idx >= G * 9) return;
    int g = idx / 9;
    int t = idx - g * 9;
    int lo = seg[g], hi = seg[g + 1];
    float4 acc = make_float4(0.f, 0.f, 0.f, 0.f);
    for (int n = lo; n < hi; ++n) {
        float4 v = *reinterpret_cast<const float4*>(h + (long long)n * 36 + 4 * t);
        acc.x += v.x; acc.y += v.y; acc.z += v.z; acc.w += v.w;
    }
    *reinterpret_cast<float4*>(pooled + (long long)g * 36 + 4 * t) = acc;
}

// ===================== MLP head =====================

__global__ void mlp1_kernel(const float* __restrict__ pooled,
                            const float* __restrict__ lw1,
                            const float* __restrict__ lb1,
                            float* __restrict__ y1,
                            int G) {
    __shared__ float Ws[36 * 96];
    for (int i = threadIdx.x; i < 36 * 96; i += blockDim.x) Ws[i] = lw1[i];
    __syncthreads();
    int idx = blockIdx.x * blockDim.x + threadIdx.x;
    if (idx >= G * 96) return;
    int g = idx / 96;
    int j = idx - g * 96;
    const float* pr = pooled + (long long)g * 36;
    float acc = lb1[j];
#pragma unroll
    for (int k4 = 0; k4 < 9; ++k4) {
        float4 pv = *reinterpret_cast<const float4*>(pr + 4 * k4);
        acc += pv.x * Ws[(4 * k4 + 0) * 96 + j];
        acc += pv.y * Ws[(4 * k4 + 1) * 96 + j];
        acc += pv.z * Ws[(4 * k4 + 2) * 96 + j];
        acc += pv.w * Ws[(4 * k4 + 3) * 96 + j];
    }
    y1[idx] = fmaxf(acc, 0.0f);
}

__global__ void mlp2_kernel(const float* __restrict__ y1,
                            const float* __restrict__ lw2,
                            const float* __restrict__ lb2,
                            float* __restrict__ out,
                            int G) {
    __shared__ float Ws[96 * 27];
    for (int i = threadIdx.x; i < 96 * 27; i += blockDim.x) Ws[i] = lw2[i];
    __syncthreads();
    int idx = blockIdx.x * blockDim.x + threadIdx.x;
    if (idx >= G * 27) return;
    int g = idx / 27;
    int c = idx - g * 27;
    const float* yr = y1 + (long long)g * 96;
    float acc = lb2[c];
#pragma unroll
    for (int k4 = 0; k4 < 24; ++k4) {
        float4 yv = *reinterpret_cast<const float4*>(yr + 4 * k4);
        acc += yv.x * Ws[(4 * k4 + 0) * 27 + c];
        acc += yv.y * Ws[(4 * k4 + 1) * 27 + c];
        acc += yv.z * Ws[(4 * k4 + 2) * 27 + c];
        acc += yv.w * Ws[(4 * k4 + 3) * 27 + c];
    }
    out[idx] = fmaxf(acc, 0.0f);
}

// ===================== launch =====================

extern "C" void kernel_launch(void* const* d_in, const int* in_sizes, int n_in,
                              void* d_out, int out_size, void* d_ws, size_t ws_size,
                              hipStream_t stream) {
    const float* x     = (const float*)d_in[0];
    const int*   ei    = (const int*)d_in[1];
    const int*   batch = (const int*)d_in[2];
    const float* W1  = (const float*)d_in[4];
    const float* b1  = (const float*)d_in[5];
    const float* W2  = (const float*)d_in[6];
    const float* b2  = (const float*)d_in[7];
    const float* W3  = (const float*)d_in[8];
    const float* b3  = (const float*)d_in[9];
    const float* W4  = (const float*)d_in[10];
    const float* b4  = (const float*)d_in[11];
    const float* lw1 = (const float*)d_in[12];
    const float* lb1 = (const float*)d_in[13];
    const float* lw2 = (const float*)d_in[14];
    const float* lb2 = (const float*)d_in[15];
    float* out = (float*)d_out;

    const int N = in_sizes[0] / 75;
    const int E = in_sizes[1] / 2;
    const int G = out_size / 27;
    const int* srcp = ei;
    const int* dstp = ei + E;

    char* ws = (char*)d_ws;
    size_t off = 0;
    auto carve = [&](size_t bytes) -> char* {
        char* p = ws + off;
        off = (off + bytes + 255) & ~(size_t)255;
        return p;
    };
    int*   cnt        = (int*)carve((size_t)N * 4);          // histogram -> cursor
    int*   row_ptr    = (int*)carve((size_t)(N + 1) * 4);
    int*   sorted_src = (int*)carve((size_t)E * 4);
    int*   bsum       = (int*)carve((size_t)cdiv(N, 1024) * 4 + 4);
    int*   seg        = (int*)carve((size_t)(G + 1) * 4);
    float* dinv       = (float*)carve((size_t)N * 4);
    float* A          = (float*)carve((size_t)N * 36 * 4);   // ping-pong buffers
    float* B          = (float*)carve((size_t)N * 36 * 4);
    float* pooled     = (float*)carve((size_t)G * 36 * 4);
    float* y1         = (float*)carve((size_t)G * 96 * 4);
    (void)ws_size; (void)n_in;

    const int BLK = 256;
    const int nb = cdiv(N, 1024);

    // ---- edge preprocessing ----
    zero_int_kernel<<<cdiv(N, BLK), BLK, 0, stream>>>(cnt, N);
    hist4_kernel<<<cdiv(cdiv(E, 4), BLK), BLK, 0, stream>>>(dstp, cnt, E);
    dinv_kernel<<<cdiv(N, BLK), BLK, 0, stream>>>(cnt, dinv, N);
    scan_partial_kernel<<<nb, 256, 0, stream>>>(cnt, bsum, N);
    if (nb <= 1024) scan_bsum_par_kernel<<<1, 1024, 0, stream>>>(bsum, nb);
    else            scan_bsum_serial_kernel<<<1, 64, 0, stream>>>(bsum, nb);
    scan_final_kernel<<<nb, 256, 0, stream>>>(cnt, bsum, row_ptr, N, E);
    zero_int_kernel<<<cdiv(N, BLK), BLK, 0, stream>>>(cnt, N);  // cursor = 0
    fill_sorted4_kernel<<<cdiv(cdiv(E, 4), BLK), BLK, 0, stream>>>(srcp, dstp, row_ptr, cnt, sorted_src, E);
    segstart_kernel<<<cdiv(G + 1, BLK), BLK, 0, stream>>>(batch, seg, N, G);

    // strides: u1=16 (64B rows), u2=20, u3=32 (128B line-aligned), u4=36
    gemm_scale_kernel<75, 75, 15, 16><<<cdiv(N, BLK), BLK, 0, stream>>>(x, W1, dinv, B, N);
    agg_gemm_kernel<16, 15, 20, 20><<<cdiv(N, BLK), BLK, 0, stream>>>(B, row_ptr, sorted_src, dinv, b1, W2, A, N);
    agg_gemm_kernel<20, 20, 27, 32><<<cdiv(N, BLK), BLK, 0, stream>>>(A, row_ptr, sorted_src, dinv, b2, W3, B, N);
    agg_gemm_kernel<32, 27, 36, 36><<<cdiv(N, BLK), BLK, 0, stream>>>(B, row_ptr, sorted_src, dinv, b3, W4, A, N);
    agg_selu_kernel<36, 36><<<cdiv(N, BLK), BLK, 0, stream>>>(A, row_ptr, sorted_src, dinv, b4, B, N);

    // ---- pool: segmented sum (batch_vec is sorted) ----
    pool_kernel<<<cdiv((long long)G * 9, BLK), BLK, 0, stream>>>(B, seg, pooled, G);

    // ---- MLP head ----
    mlp1_kernel<<<cdiv((long long)G * 96, BLK), BLK, 0, stream>>>(pooled, lw1, lb1, y1, G);
    mlp2_kernel<<<cdiv((long long)G * 27, BLK), BLK, 0, stream>>>(y1, lw2, lb2, out, G);
}

// Round 6
// 1146.807 us; speedup vs baseline: 14.8725x; 1.1513x over previous
//
#include <hip/hip_runtime.h>
#include <hip/hip_fp16.h>
#include <math.h>

#define SELU_SCALE 1.0507009873554805f
#define SELU_ALPHA 1.6732632423543772f

static inline int cdiv(long long a, int b) { return (int)((a + b - 1) / b); }

// ===================== edge preprocessing =====================

__global__ void zero_int_kernel(int* __restrict__ p, int n) {
    int i = blockIdx.x * blockDim.x + threadIdx.x;
    if (i < n) p[i] = 0;
}

__global__ void hist4_kernel(const int* __restrict__ dst, int* __restrict__ cnt, int E) {
    int i = blockIdx.x * blockDim.x + threadIdx.x;
    int base = i * 4;
    if (base + 3 < E) {
        int4 d = *reinterpret_cast<const int4*>(dst + base);
        atomicAdd(&cnt[d.x], 1);
        atomicAdd(&cnt[d.y], 1);
        atomicAdd(&cnt[d.z], 1);
        atomicAdd(&cnt[d.w], 1);
    } else {
        for (int e = base; e < E; ++e) atomicAdd(&cnt[dst[e]], 1);
    }
}

__global__ void dinv_kernel(const int* __restrict__ cnt, float* __restrict__ dinv, int N) {
    int i = blockIdx.x * blockDim.x + threadIdx.x;
    if (i < N) dinv[i] = rsqrtf((float)cnt[i] + 1.0f);  // +1 self loop
}

__global__ void scan_partial_kernel(const int* __restrict__ cnt, int* __restrict__ bsum, int N) {
    __shared__ int sh[256];
    int base = blockIdx.x * 1024;
    int t = threadIdx.x;
    int s = 0;
#pragma unroll
    for (int k = 0; k < 4; ++k) {
        int i = base + t * 4 + k;
        if (i < N) s += cnt[i];
    }
    sh[t] = s;
    __syncthreads();
    for (int o = 128; o > 0; o >>= 1) {
        if (t < o) sh[t] += sh[t + o];
        __syncthreads();
    }
    if (t == 0) bsum[blockIdx.x] = sh[0];
}

__global__ void scan_bsum_par_kernel(int* __restrict__ bsum, int nb) {
    __shared__ int sh[1024];
    int t = threadIdx.x;
    int v = (t < nb) ? bsum[t] : 0;
    sh[t] = v;
    __syncthreads();
    for (int o = 1; o < 1024; o <<= 1) {
        int y = (t >= o) ? sh[t - o] : 0;
        __syncthreads();
        sh[t] += y;
        __syncthreads();
    }
    if (t < nb) bsum[t] = sh[t] - v;
}

__global__ void scan_bsum_serial_kernel(int* __restrict__ bsum, int nb) {
    if (blockIdx.x == 0 && threadIdx.x == 0) {
        int acc = 0;
        for (int i = 0; i < nb; ++i) { int v = bsum[i]; bsum[i] = acc; acc += v; }
    }
}

__global__ void scan_final_kernel(const int* __restrict__ cnt, const int* __restrict__ bsum,
                                  int* __restrict__ row_ptr, int N, int E) {
    __shared__ int sh[256];
    int base = blockIdx.x * 1024;
    int t = threadIdx.x;
    int i0 = base + t * 4;
    int v0 = (i0 + 0 < N) ? cnt[i0 + 0] : 0;
    int v1 = (i0 + 1 < N) ? cnt[i0 + 1] : 0;
    int v2 = (i0 + 2 < N) ? cnt[i0 + 2] : 0;
    int v3 = (i0 + 3 < N) ? cnt[i0 + 3] : 0;
    sh[t] = v0 + v1 + v2 + v3;
    __syncthreads();
    for (int o = 1; o < 256; o <<= 1) {
        int y = (t >= o) ? sh[t - o] : 0;
        __syncthreads();
        sh[t] += y;
        __syncthreads();
    }
    int off = bsum[blockIdx.x] + ((t > 0) ? sh[t - 1] : 0);
    if (i0 + 0 < N) row_ptr[i0 + 0] = off;  off += v0;
    if (i0 + 1 < N) row_ptr[i0 + 1] = off;  off += v1;
    if (i0 + 2 < N) row_ptr[i0 + 2] = off;  off += v2;
    if (i0 + 3 < N) row_ptr[i0 + 3] = off;
    if (blockIdx.x == 0 && t == 0) row_ptr[N] = E;
}

__global__ void fill_sorted4_kernel(const int* __restrict__ src, const int* __restrict__ dst,
                                    const int* __restrict__ row_ptr, int* __restrict__ cursor,
                                    int* __restrict__ sorted_src, int E) {
    int i = blockIdx.x * blockDim.x + threadIdx.x;
    int base = i * 4;
    if (base + 3 < E) {
        int4 d = *reinterpret_cast<const int4*>(dst + base);
        int4 s = *reinterpret_cast<const int4*>(src + base);
        int r0 = row_ptr[d.x];
        int r1 = row_ptr[d.y];
        int r2 = row_ptr[d.z];
        int r3 = row_ptr[d.w];
        int k0 = atomicAdd(&cursor[d.x], 1);
        int k1 = atomicAdd(&cursor[d.y], 1);
        int k2 = atomicAdd(&cursor[d.z], 1);
        int k3 = atomicAdd(&cursor[d.w], 1);
        sorted_src[r0 + k0] = s.x;
        sorted_src[r1 + k1] = s.y;
        sorted_src[r2 + k2] = s.z;
        sorted_src[r3 + k3] = s.w;
    } else {
        for (int e = base; e < E; ++e) {
            int dd = dst[e];
            int pos = row_ptr[dd] + atomicAdd(&cursor[dd], 1);
            sorted_src[pos] = src[e];
        }
    }
}

// ===================== fp16 row helpers =====================
// rows stored as __half with stride SH (multiple of 8 -> 16B-aligned rows)

template <int SH>
__device__ __forceinline__ void load_row_h(float* __restrict__ acc, const __half* __restrict__ row) {
#pragma unroll
    for (int u = 0; u < SH / 8; ++u) {
        union { float4 f4; __half2 h2[4]; } ld;
        ld.f4 = *reinterpret_cast<const float4*>(row + u * 8);
#pragma unroll
        for (int k = 0; k < 4; ++k) {
            float2 f = __half22float2(ld.h2[k]);
            acc[u * 8 + 2 * k + 0] = f.x;
            acc[u * 8 + 2 * k + 1] = f.y;
        }
    }
}

template <int SH>
__device__ __forceinline__ void fmax_row_h(float* __restrict__ acc, const __half* __restrict__ row) {
#pragma unroll
    for (int u = 0; u < SH / 8; ++u) {
        union { float4 f4; __half2 h2[4]; } ld;
        ld.f4 = *reinterpret_cast<const float4*>(row + u * 8);
#pragma unroll
        for (int k = 0; k < 4; ++k) {
            float2 f = __half22float2(ld.h2[k]);
            acc[u * 8 + 2 * k + 0] = fmaxf(acc[u * 8 + 2 * k + 0], f.x);
            acc[u * 8 + 2 * k + 1] = fmaxf(acc[u * 8 + 2 * k + 1], f.y);
        }
    }
}

template <int FOUT, int SOUTH>
__device__ __forceinline__ void store_row_h(__half* __restrict__ op,
                                            const float* __restrict__ vals, float dv) {
#pragma unroll
    for (int u = 0; u < SOUTH / 8; ++u) {
        union { float4 f4; __half2 h2[4]; } pk;
#pragma unroll
        for (int k = 0; k < 4; ++k) {
            int f0 = u * 8 + 2 * k, f1 = f0 + 1;
            float a = (f0 < FOUT) ? vals[f0] * dv : 0.0f;
            float b = (f1 < FOUT) ? vals[f1] * dv : 0.0f;
            pk.h2[k] = __floats2half2_rn(a, b);
        }
        *reinterpret_cast<float4*>(op + u * 8) = pk.f4;
    }
}

// ===================== layer kernels =====================

// layer-1 GEMM: u1[n,:] = half((x[n,:] @ W1) * dinv[n]), stride SOUTH halves
template <int FIN, int FOUT, int SOUTH>
__global__ void gemm_scale_kernel(const float* __restrict__ h,
                                  const float* __restrict__ W,
                                  const float* __restrict__ dinv,
                                  __half* __restrict__ u,
                                  int N) {
    int n = blockIdx.x * blockDim.x + threadIdx.x;
    if (n >= N) return;
    const float* hr = h + (long long)n * FIN;
    float acc[FOUT];
#pragma unroll
    for (int c = 0; c < FOUT; ++c) acc[c] = 0.0f;
#pragma unroll
    for (int fi = 0; fi < FIN; ++fi) {
        float hv = hr[fi];
#pragma unroll
        for (int c = 0; c < FOUT; ++c) acc[c] += hv * W[fi * FOUT + c];
    }
    store_row_h<FOUT, SOUTH>(u + (long long)n * SOUTH, acc, dinv[n]);
}

// fused: h = selu(dinv*max(...) + bprev); uout = half((h @ W)*dinv)
template <int SPREVH, int FPREV, int FOUT, int SOUTH>
__global__ void agg_gemm_kernel(const __half* __restrict__ u,
                                const int* __restrict__ row_ptr,
                                const int* __restrict__ sorted_src,
                                const float* __restrict__ dinv,
                                const float* __restrict__ bprev,
                                const float* __restrict__ W,
                                __half* __restrict__ uout,
                                int N) {
    int n = blockIdx.x * blockDim.x + threadIdx.x;
    if (n >= N) return;
    float acc[SPREVH];
    load_row_h<SPREVH>(acc, u + (long long)n * SPREVH);  // self loop
    int j0 = row_ptr[n], j1 = row_ptr[n + 1];
    int j = j0;
    for (; j + 1 < j1; j += 2) {
        const __half* r0 = u + (long long)sorted_src[j] * SPREVH;
        const __half* r1 = u + (long long)sorted_src[j + 1] * SPREVH;
        fmax_row_h<SPREVH>(acc, r0);
        fmax_row_h<SPREVH>(acc, r1);
    }
    if (j < j1) fmax_row_h<SPREVH>(acc, u + (long long)sorted_src[j] * SPREVH);

    float dv = dinv[n];
    float h[FPREV];
#pragma unroll
    for (int f = 0; f < FPREV; ++f) {
        float v = dv * acc[f] + bprev[f];
        h[f] = (v > 0.0f) ? (SELU_SCALE * v) : (SELU_SCALE * SELU_ALPHA * (expf(v) - 1.0f));
    }
    float out[FOUT];
#pragma unroll
    for (int c = 0; c < FOUT; ++c) out[c] = 0.0f;
#pragma unroll
    for (int fi = 0; fi < FPREV; ++fi) {
        float hv = h[fi];
#pragma unroll
        for (int c = 0; c < FOUT; ++c) out[c] += hv * W[fi * FOUT + c];
    }
    store_row_h<FOUT, SOUTH>(uout + (long long)n * SOUTH, out, dv);
}

// final aggregation (layer 4): fp32 output stride F for pooling
template <int SH, int F>
__global__ void agg_selu_kernel(const __half* __restrict__ u,
                                const int* __restrict__ row_ptr,
                                const int* __restrict__ sorted_src,
                                const float* __restrict__ dinv,
                                const float* __restrict__ b,
                                float* __restrict__ hout,
                                int N) {
    int n = blockIdx.x * blockDim.x + threadIdx.x;
    if (n >= N) return;
    float acc[SH];
    load_row_h<SH>(acc, u + (long long)n * SH);
    int j0 = row_ptr[n], j1 = row_ptr[n + 1];
    int j = j0;
    for (; j + 1 < j1; j += 2) {
        const __half* r0 = u + (long long)sorted_src[j] * SH;
        const __half* r1 = u + (long long)sorted_src[j + 1] * SH;
        fmax_row_h<SH>(acc, r0);
        fmax_row_h<SH>(acc, r1);
    }
    if (j < j1) fmax_row_h<SH>(acc, u + (long long)sorted_src[j] * SH);

    float dv = dinv[n];
    float* op = hout + (long long)n * F;
#pragma unroll
    for (int q = 0; q < F / 4; ++q) {
        float4 o;
        float* ov = &o.x;
#pragma unroll
        for (int k = 0; k < 4; ++k) {
            int f = 4 * q + k;
            float v = dv * acc[f] + b[f];
            ov[k] = (v > 0.0f) ? (SELU_SCALE * v) : (SELU_SCALE * SELU_ALPHA * (expf(v) - 1.0f));
        }
        *reinterpret_cast<float4*>(op + 4 * q) = o;
    }
}

// ===================== pooling =====================

__global__ void segstart_kernel(const int* __restrict__ batch, int* __restrict__ seg, int N, int G) {
    int g = blockIdx.x * blockDim.x + threadIdx.x;
    if (g > G) return;
    if (g == G) { seg[G] = N; return; }
    int lo = 0, hi = N;
    while (lo < hi) { int mid = (lo + hi) >> 1; if (batch[mid] < g) lo = mid + 1; else hi = mid; }
    seg[g] = lo;
}

__global__ void pool_kernel(const float* __restrict__ h,
                            const int* __restrict__ seg,
                            float* __restrict__ pooled,
                            int G) {
    int idx = blockIdx.x * blockDim.x + threadIdx.x;  // G * 9
    if (idx >= G * 9) return;
    int g = idx / 9;
    int t = idx - g * 9;
    int lo = seg[g], hi = seg[g + 1];
    float4 acc = make_float4(0.f, 0.f, 0.f, 0.f);
    for (int n = lo; n < hi; ++n) {
        float4 v = *reinterpret_cast<const float4*>(h + (long long)n * 36 + 4 * t);
        acc.x += v.x; acc.y += v.y; acc.z += v.z; acc.w += v.w;
    }
    *reinterpret_cast<float4*>(pooled + (long long)g * 36 + 4 * t) = acc;
}

// ===================== MLP head =====================

__global__ void mlp1_kernel(const float* __restrict__ pooled,
                            const float* __restrict__ lw1,
                            const float* __restrict__ lb1,
                            float* __restrict__ y1,
                            int G) {
    __shared__ float Ws[36 * 96];
    for (int i = threadIdx.x; i < 36 * 96; i += blockDim.x) Ws[i] = lw1[i];
    __syncthreads();
    int idx = blockIdx.x * blockDim.x + threadIdx.x;
    if (idx >= G * 96) return;
    int g = idx / 96;
    int j = idx - g * 96;
    const float* pr = pooled + (long long)g * 36;
    float acc = lb1[j];
#pragma unroll
    for (int k4 = 0; k4 < 9; ++k4) {
        float4 pv = *reinterpret_cast<const float4*>(pr + 4 * k4);
        acc += pv.x * Ws[(4 * k4 + 0) * 96 + j];
        acc += pv.y * Ws[(4 * k4 + 1) * 96 + j];
        acc += pv.z * Ws[(4 * k4 + 2) * 96 + j];
        acc += pv.w * Ws[(4 * k4 + 3) * 96 + j];
    }
    y1[idx] = fmaxf(acc, 0.0f);
}

__global__ void mlp2_kernel(const float* __restrict__ y1,
                            const float* __restrict__ lw2,
                            const float* __restrict__ lb2,
                            float* __restrict__ out,
                            int G) {
    __shared__ float Ws[96 * 27];
    for (int i = threadIdx.x; i < 96 * 27; i += blockDim.x) Ws[i] = lw2[i];
    __syncthreads();
    int idx = blockIdx.x * blockDim.x + threadIdx.x;
    if (idx >= G * 27) return;
    int g = idx / 27;
    int c = idx - g * 27;
    const float* yr = y1 + (long long)g * 96;
    float acc = lb2[c];
#pragma unroll
    for (int k4 = 0; k4 < 24; ++k4) {
        float4 yv = *reinterpret_cast<const float4*>(yr + 4 * k4);
        acc += yv.x * Ws[(4 * k4 + 0) * 27 + c];
        acc += yv.y * Ws[(4 * k4 + 1) * 27 + c];
        acc += yv.z * Ws[(4 * k4 + 2) * 27 + c];
        acc += yv.w * Ws[(4 * k4 + 3) * 27 + c];
    }
    out[idx] = fmaxf(acc, 0.0f);
}

// ===================== launch =====================

extern "C" void kernel_launch(void* const* d_in, const int* in_sizes, int n_in,
                              void* d_out, int out_size, void* d_ws, size_t ws_size,
                              hipStream_t stream) {
    const float* x     = (const float*)d_in[0];
    const int*   ei    = (const int*)d_in[1];
    const int*   batch = (const int*)d_in[2];
    const float* W1  = (const float*)d_in[4];
    const float* b1  = (const float*)d_in[5];
    const float* W2  = (const float*)d_in[6];
    const float* b2  = (const float*)d_in[7];
    const float* W3  = (const float*)d_in[8];
    const float* b3  = (const float*)d_in[9];
    const float* W4  = (const float*)d_in[10];
    const float* b4  = (const float*)d_in[11];
    const float* lw1 = (const float*)d_in[12];
    const float* lb1 = (const float*)d_in[13];
    const float* lw2 = (const float*)d_in[14];
    const float* lb2 = (const float*)d_in[15];
    float* out = (float*)d_out;

    const int N = in_sizes[0] / 75;
    const int E = in_sizes[1] / 2;
    const int G = out_size / 27;
    const int* srcp = ei;
    const int* dstp = ei + E;

    char* ws = (char*)d_ws;
    size_t off = 0;
    auto carve = [&](size_t bytes) -> char* {
        char* p = ws + off;
        off = (off + bytes + 255) & ~(size_t)255;
        return p;
    };
    int*    cnt        = (int*)carve((size_t)N * 4);
    int*    row_ptr    = (int*)carve((size_t)(N + 1) * 4);
    int*    sorted_src = (int*)carve((size_t)E * 4);
    int*    bsum       = (int*)carve((size_t)cdiv(N, 1024) * 4 + 4);
    int*    seg        = (int*)carve((size_t)(G + 1) * 4);
    float*  dinv       = (float*)carve((size_t)N * 4);
    // ping-pong buffers big enough for: fp16 rows (max 40 halves = 80 B) or fp32 h4 (36 floats = 144 B)
    char*   Abuf       = carve((size_t)N * 36 * 4);
    char*   Bbuf       = carve((size_t)N * 36 * 4);
    float*  pooled     = (float*)carve((size_t)G * 36 * 4);
    float*  y1         = (float*)carve((size_t)G * 96 * 4);
    (void)ws_size; (void)n_in;

    const int BLK = 256;
    const int nb = cdiv(N, 1024);

    // ---- edge preprocessing ----
    zero_int_kernel<<<cdiv(N, BLK), BLK, 0, stream>>>(cnt, N);
    hist4_kernel<<<cdiv(cdiv(E, 4), BLK), BLK, 0, stream>>>(dstp, cnt, E);
    dinv_kernel<<<cdiv(N, BLK), BLK, 0, stream>>>(cnt, dinv, N);
    scan_partial_kernel<<<nb, 256, 0, stream>>>(cnt, bsum, N);
    if (nb <= 1024) scan_bsum_par_kernel<<<1, 1024, 0, stream>>>(bsum, nb);
    else            scan_bsum_serial_kernel<<<1, 64, 0, stream>>>(bsum, nb);
    scan_final_kernel<<<nb, 256, 0, stream>>>(cnt, bsum, row_ptr, N, E);
    zero_int_kernel<<<cdiv(N, BLK), BLK, 0, stream>>>(cnt, N);  // cursor = 0
    fill_sorted4_kernel<<<cdiv(cdiv(E, 4), BLK), BLK, 0, stream>>>(srcp, dstp, row_ptr, cnt, sorted_src, E);
    segstart_kernel<<<cdiv(G + 1, BLK), BLK, 0, stream>>>(batch, seg, N, G);

    // fp16 u strides (halves): u1=16 (32B), u2=32 (64B line), u3=32 (64B line), u4=40 (80B)
    __half* u1 = (__half*)Bbuf;
    __half* u2 = (__half*)Abuf;
    __half* u3 = (__half*)Bbuf;
    __half* u4 = (__half*)Abuf;
    float*  h4 = (float*)Bbuf;

    gemm_scale_kernel<75, 15, 16><<<cdiv(N, BLK), BLK, 0, stream>>>(x, W1, dinv, u1, N);
    agg_gemm_kernel<16, 15, 20, 32><<<cdiv(N, BLK), BLK, 0, stream>>>(u1, row_ptr, sorted_src, dinv, b1, W2, u2, N);
    agg_gemm_kernel<32, 20, 27, 32><<<cdiv(N, BLK), BLK, 0, stream>>>(u2, row_ptr, sorted_src, dinv, b2, W3, u3, N);
    agg_gemm_kernel<32, 27, 36, 40><<<cdiv(N, BLK), BLK, 0, stream>>>(u3, row_ptr, sorted_src, dinv, b3, W4, u4, N);
    agg_selu_kernel<40, 36><<<cdiv(N, BLK), BLK, 0, stream>>>(u4, row_ptr, sorted_src, dinv, b4, h4, N);

    // ---- pool: segmented sum (batch_vec is sorted) ----
    pool_kernel<<<cdiv((long long)G * 9, BLK), BLK, 0, stream>>>(h4, seg, pooled, G);

    // ---- MLP head ----
    mlp1_kernel<<<cdiv((long long)G * 96, BLK), BLK, 0, stream>>>(pooled, lw1, lb1, y1, G);
    mlp2_kernel<<<cdiv((long long)G * 27, BLK), BLK, 0, stream>>>(y1, lw2, lb2, out, G);
}